// Round 1
// baseline (293.051 us; speedup 1.0000x reference)
//
#include <hip/hip_runtime.h>
#include <stdint.h>

// Problem constants: B=4, S=2048, D=1024, H=1024, heads=16, d_k=64.
// Pipeline: fused cast->bf16, fused QKV GEMM (256^2-tile counted-vmcnt
// pipelined MFMA, LDS-bounced coalesced epilogues, V transposed per head),
// flash attention (MFMA, no-max exp2 softmax, S^T trick, MFMA row-sums,
// 256-q tile / 8 waves, single-barrier dbuf K/V prefetch),
// out GEMM (m97 2-barrier, f32 out).
// LDS tiles XOR-swizzled (granule g of row r at g^(r&7)) -> conflict-free b128.

using bf16x8 = __attribute__((ext_vector_type(8))) short;   // 8 bf16 = 4 VGPRs
using f32x4  = __attribute__((ext_vector_type(4))) float;   // MFMA C/D frag

#define QSCALE 0.18033688f  // 1/sqrt(64) * log2(e): scores come out log2-scaled -> exp2

__device__ __forceinline__ unsigned short f2bf(float f) {
    unsigned u = __builtin_bit_cast(unsigned, f);
    u += 0x7fffu + ((u >> 16) & 1u);          // RNE
    return (unsigned short)(u >> 16);
}

// pack two f32 -> two bf16 in one dword: round-to-nearest (ties away) + v_perm
__device__ __forceinline__ unsigned pack2bf(float f0, float f1) {
    unsigned u0 = __builtin_bit_cast(unsigned, f0) + 0x8000u;
    unsigned u1 = __builtin_bit_cast(unsigned, f1) + 0x8000u;
    return __builtin_amdgcn_perm(u1, u0, 0x07060302);  // {hi16(u1),hi16(u0)}
}

// async global->LDS, 16B per lane; LDS dest = wave-uniform base + lane*16
__device__ __forceinline__ void gld16(const void* g, void* l) {
    void* gnc = (void*)g;
    __builtin_amdgcn_global_load_lds((__attribute__((address_space(1))) void*)gnc,
                                     (__attribute__((address_space(3))) void*)l,
                                     16, 0, 0);
}

// swizzled LDS short-offset for (row R, 16B-granule g) in a 64-short-row tile
__device__ __forceinline__ int swz(int R, int g) {
    return R * 64 + ((g ^ (R & 7)) << 3);
}

// ---------------------------------------------------------------- fused casts
__global__ void castall(const float* __restrict__ X, const float* __restrict__ Wq,
                        const float* __restrict__ Wk, const float* __restrict__ Wv,
                        const float* __restrict__ Wo, unsigned short* __restrict__ Xb,
                        unsigned short* __restrict__ Wqkvb, unsigned short* __restrict__ Wob) {
    const int bx = blockIdx.x;
    const float* src; unsigned short* dst; int idx;
    if (bx < 8192) { src = X; dst = Xb; idx = bx * 256 + threadIdx.x; }
    else {
        const int r = bx - 8192, w = r >> 10;
        idx = (r & 1023) * 256 + threadIdx.x;
        src = (w == 0) ? Wq : (w == 1) ? Wk : (w == 2) ? Wv : Wo;
        dst = (w == 3) ? Wob : Wqkvb + (size_t)w * 1048576;
    }
    float4 v = ((const float4*)src)[idx];
    ((uint2*)dst)[idx] = make_uint2(pack2bf(v.x, v.y), pack2bf(v.z, v.w));
}

// ---------------------------------------------------------------- fused QKV GEMM
// A: (8192,1024) bf16. Wqkv: 3 stacked (1024,1024) bf16 = one (3072,1024).
// 256x256 tile, BK=64, 8 waves (2Mx4N, per-wave 128x64), 128 KiB LDS dbuf.
// Counted-vmcnt 4-phase schedule per K-tile t (buf b = t&1):
//   ph0: read B(all 8 frags)+A(m0,m1); stage (t+1).A0 -> buf b^1
//   ph1: read A(m2,m3);               stage (t+1).A1 -> buf b^1
//   ph2: read A(m4,m5);               stage (t+2).B0 -> buf b   (B consumed @ph0)
//   ph3: read A(m6,m7);               stage (t+2).B1 -> buf b ; s_waitcnt vmcnt(4)
//   each phase: barrier; lgkmcnt(0); setprio(1); 16 MFMA; setprio(0); barrier
// vmcnt(4) leaves only the 2 just-issued B-halves in flight and certifies
// tile t+1 complete (its halves were issued >=2 phases earlier). Stage-write
// safety: every stage targets a slot whose last reader passed a barrier that
// precedes the stage issue. Epilogue bounces acc through the dead 128 KiB
// staging LDS (2 x 128-row passes) for coalesced b128 stores; Q scaled by
// QSCALE; V stored transposed per head: Vt[(b*1024 + n)*2048 + s].
__global__ __launch_bounds__(512, 2) void gemm_qkv(const unsigned short* __restrict__ A,
                                                   const unsigned short* __restrict__ Wqkv,
                                                   const float* __restrict__ bq,
                                                   const float* __restrict__ bk,
                                                   const float* __restrict__ bv,
                                                   unsigned short* __restrict__ Qb,
                                                   unsigned short* __restrict__ Kb,
                                                   unsigned short* __restrict__ Vt) {
    __shared__ alignas(16) unsigned short smem[65536];   // 128 KiB: [buf][A|B][256][64]

    const int tid  = threadIdx.x;
    const int lane = tid & 63;
    const int w    = tid >> 6;          // wave 0..7
    const int quad = lane >> 4;
    const int l15  = lane & 15;
    const int lr   = lane >> 3;
    const int lcs  = (((lane & 7) ^ lr) << 3);
    const int wm   = w >> 2;            // 0..1  (M position, 128 rows)
    const int wn   = w & 3;             // 0..3  (N position, 64 cols)

    const int col0 = blockIdx.x * 256;   // output col / W row
    const int row0 = blockIdx.y * 256;   // token row

    // per-thread staging source bases (row group i=0); +8*1024 shorts for i=1
    const unsigned short* aS = A    + (size_t)(row0 + w * 16 + lr) * 1024 + lcs;
    const unsigned short* bS = Wqkv + (size_t)(col0 + w * 16 + lr) * 1024 + lcs;
    const int dstW = w * 1024;          // wave's 16-row slice within a 128-row half

// stage one half-tile (128 rows x 64 k) : 2 x gld16 per thread
#define STG_A(t_, h_, b_)                                                              \
    { const unsigned short* s_ = aS + (size_t)(h_) * 131072 + (t_) * 64;               \
      gld16(s_,            &smem[(b_) * 32768 + (h_) * 8192 + dstW]);                  \
      gld16(s_ + 8 * 1024, &smem[(b_) * 32768 + (h_) * 8192 + dstW + 512]); }
#define STG_B(t_, h_, b_)                                                              \
    { const unsigned short* s_ = bS + (size_t)(h_) * 131072 + (t_) * 64;               \
      gld16(s_,            &smem[(b_) * 32768 + 16384 + (h_) * 8192 + dstW]);          \
      gld16(s_ + 8 * 1024, &smem[(b_) * 32768 + 16384 + (h_) * 8192 + dstW + 512]); }

    f32x4 acc[8][4];
#pragma unroll
    for (int i = 0; i < 8; i++)
#pragma unroll
        for (int j = 0; j < 4; j++) acc[i][j] = f32x4{0.f, 0.f, 0.f, 0.f};

    // prologue: tile0 fully + tile1's B halves; wait tile0 (leave T1.B in flight)
    STG_A(0, 0, 0) STG_A(0, 1, 0) STG_B(0, 0, 0) STG_B(0, 1, 0)
    STG_B(1, 0, 1) STG_B(1, 1, 1)
    asm volatile("s_waitcnt vmcnt(4)" ::: "memory");
    __builtin_amdgcn_s_barrier();

    for (int t = 0; t < 16; ++t) {
        const int b = t & 1;
        unsigned short* bufA = smem + b * 32768;
        unsigned short* bufB = bufA + 16384;
        bf16x8 bfr[4][2];
#pragma unroll
        for (int p = 0; p < 4; ++p) {
            bf16x8 afr[2][2];
            if (p == 0) {
#pragma unroll
                for (int nf = 0; nf < 4; ++nf)
#pragma unroll
                    for (int kx = 0; kx < 2; ++kx)
                        bfr[nf][kx] = *(const bf16x8*)&bufB[swz(wn * 64 + nf * 16 + l15, kx * 4 + quad)];
            }
#pragma unroll
            for (int mi = 0; mi < 2; ++mi)
#pragma unroll
                for (int kx = 0; kx < 2; ++kx)
                    afr[mi][kx] = *(const bf16x8*)&bufA[swz(wm * 128 + (p * 2 + mi) * 16 + l15, kx * 4 + quad)];

            if (p == 0)      { if (t < 15) STG_A(t + 1, 0, b ^ 1) }
            else if (p == 1) { if (t < 15) STG_A(t + 1, 1, b ^ 1) }
            else if (p == 2) { if (t < 14) STG_B(t + 2, 0, b) }
            else {
                if (t < 14) {
                    STG_B(t + 2, 1, b)
                    asm volatile("s_waitcnt vmcnt(4)" ::: "memory");
                } else if (t == 14) {
                    asm volatile("s_waitcnt vmcnt(0)" ::: "memory");
                }
            }
            __builtin_amdgcn_s_barrier();
            asm volatile("s_waitcnt lgkmcnt(0)" ::: "memory");
            __builtin_amdgcn_sched_barrier(0);
            __builtin_amdgcn_s_setprio(1);
#pragma unroll
            for (int kx = 0; kx < 2; ++kx)
#pragma unroll
                for (int mi = 0; mi < 2; ++mi)
#pragma unroll
                    for (int nf = 0; nf < 4; ++nf)
                        acc[p * 2 + mi][nf] = __builtin_amdgcn_mfma_f32_16x16x32_bf16(
                            afr[mi][kx], bfr[nf][kx], acc[p * 2 + mi][nf], 0, 0, 0);
            __builtin_amdgcn_s_setprio(0);
            __builtin_amdgcn_s_barrier();
        }
    }
#undef STG_A
#undef STG_B

    // ---- epilogue: bounce through LDS (dead staging buffers) for b128 stores
    const int nb   = col0 >> 10;             // 0=Q 1=K 2=V
    const int colq = col0 & 1023;
    const float* bias = (nb == 0) ? bq : (nb == 1) ? bk : bv;

    if (nb != 2) {
        const float sc = (nb == 0) ? QSCALE : 1.0f;
        unsigned short* C = (nb == 0) ? Qb : Kb;
#pragma unroll
        for (int h = 0; h < 2; ++h) {
            if (wm == h) {                   // OT[128][264]: rows of this half
#pragma unroll
                for (int mf = 0; mf < 8; ++mf)
#pragma unroll
                    for (int nf = 0; nf < 4; ++nf) {
                        const int ct  = wn * 64 + nf * 16 + l15;
                        const float bvv = bias[colq + ct];
                        const int rt  = mf * 16 + quad * 4;
#pragma unroll
                        for (int r = 0; r < 4; ++r)
                            smem[(rt + r) * 264 + ct] = f2bf((acc[mf][nf][r] + bvv) * sc);
                    }
            }
            __syncthreads();
            const int rr = tid >> 2, qq = tid & 3;
            unsigned short* gdst = C + (size_t)(row0 + h * 128 + rr) * 1024 + colq + qq * 64;
#pragma unroll
            for (int j = 0; j < 8; ++j)
                *(bf16x8*)(gdst + j * 8) = *(const bf16x8*)&smem[rr * 264 + qq * 64 + j * 8];
            if (h == 0) __syncthreads();
        }
    } else {
        const int bb = row0 >> 11, s0 = row0 & 2047;
#pragma unroll
        for (int h = 0; h < 2; ++h) {
            if (wm == h) {                   // OT[256][136]: transposed (d, s) half
#pragma unroll
                for (int mf = 0; mf < 8; ++mf)
#pragma unroll
                    for (int nf = 0; nf < 4; ++nf) {
                        const int ct  = wn * 64 + nf * 16 + l15;
                        const float bvv = bias[colq + ct];
                        const int st  = mf * 16 + quad * 4;
                        *(uint2*)&smem[ct * 136 + st] =
                            make_uint2(pack2bf(acc[mf][nf][0] + bvv, acc[mf][nf][1] + bvv),
                                       pack2bf(acc[mf][nf][2] + bvv, acc[mf][nf][3] + bvv));
                    }
            }
            __syncthreads();
            const int c = tid >> 1, hs = tid & 1;
            unsigned short* gdst = Vt + ((size_t)(bb * 1024 + colq + c)) * 2048 + s0 + h * 128 + hs * 64;
#pragma unroll
            for (int j = 0; j < 8; ++j)
                *(bf16x8*)(gdst + j * 8) = *(const bf16x8*)&smem[c * 136 + hs * 64 + j * 8];
            if (h == 0) __syncthreads();
        }
    }
}

// ---------------------------------------------------------------- out GEMM (f32 out)
// R4 form (2-barrier m97): R5's dbuf variant regressed ~14us.
__global__ __launch_bounds__(256) void gemm_out(const unsigned short* __restrict__ A,
                                                const unsigned short* __restrict__ W,
                                                const float* __restrict__ bias,
                                                float* __restrict__ C) {
    __shared__ alignas(16) unsigned short sA[128 * 64];
    __shared__ alignas(16) unsigned short sB[128 * 64];
    const int tid  = threadIdx.x;
    const int lane = tid & 63;
    const int wave = tid >> 6;
    const int quad = lane >> 4;
    const int l15  = lane & 15;
    const int lr   = lane >> 3;
    const int lcs  = (((lane & 7) ^ lr) << 3);
    const int row0 = blockIdx.y * 128;
    const int col0 = blockIdx.x * 128;
    const int wm = wave >> 1, wn = wave & 1;

    f32x4 acc[4][4];
#pragma unroll
    for (int i = 0; i < 4; i++)
#pragma unroll
        for (int j = 0; j < 4; j++) acc[i][j] = f32x4{0.f, 0.f, 0.f, 0.f};

    for (int kt = 0; kt < 16; ++kt) {
        const int k0 = kt * 64;
#pragma unroll
        for (int i = 0; i < 4; i++) {
            const int c = wave * 4 + i;
            const int r = c * 8 + lr;
            gld16(A + (size_t)(row0 + r) * 1024 + k0 + lcs, &sA[c * 512]);
            gld16(W + (size_t)(col0 + r) * 1024 + k0 + lcs, &sB[c * 512]);
        }
        __syncthreads();
#pragma unroll
        for (int kx = 0; kx < 2; ++kx) {
            bf16x8 a[4], b[4];
#pragma unroll
            for (int i = 0; i < 4; i++) {
                a[i] = *(const bf16x8*)&sA[swz(wm * 64 + i * 16 + l15, kx * 4 + quad)];
                b[i] = *(const bf16x8*)&sB[swz(wn * 64 + i * 16 + l15, kx * 4 + quad)];
            }
#pragma unroll
            for (int i = 0; i < 4; i++)
#pragma unroll
                for (int j = 0; j < 4; j++)
                    acc[i][j] = __builtin_amdgcn_mfma_f32_16x16x32_bf16(a[i], b[j], acc[i][j], 0, 0, 0);
        }
        __syncthreads();
    }

#pragma unroll
    for (int i = 0; i < 4; i++) {
#pragma unroll
        for (int j = 0; j < 4; j++) {
            const int col   = col0 + wn * 64 + j * 16 + l15;
            const float bvv = bias[col];
            const int rbase = row0 + wm * 64 + i * 16 + quad * 4;
#pragma unroll
            for (int r = 0; r < 4; r++)
                C[(size_t)(rbase + r) * 1024 + col] = acc[i][j][r] + bvv;
        }
    }
}

// ---------------------------------------------------------------- flash attention
// Q, K: (B*S, 1024) bf16; Q pre-scaled by QSCALE (fold softmax scale + log2e).
// Vt: (B*1024, 2048) bf16. Ctx out: (B*S, 1024) bf16.
// Block: 256 q-rows of one (b,h), 8 waves (512 thr); wave owns 32 q-rows.
// 32 k-tiles of 64. Single-barrier dbuf prefetch. Row-sums via MFMA
// (Osum += P @ ones) -> no scalar adds, no epilogue shuffle reduction.
__global__ __launch_bounds__(512) void attn(const unsigned short* __restrict__ Q,
                                            const unsigned short* __restrict__ K,
                                            const unsigned short* __restrict__ Vt,
                                            unsigned short* __restrict__ Ctx) {
    __shared__ alignas(16) unsigned short Kl[2][4096];     // [buf][krow][d], swizzled (8KB ea)
    __shared__ alignas(16) unsigned short Vl[2][4096];     // [buf][d][krow], swizzled
    __shared__ alignas(16) unsigned short Pl[8][32][72];   // per-wave P (36KB)

    const int tid  = threadIdx.x;
    const int lane = tid & 63;
    const int wave = tid >> 6;        // 0..7
    const int quad = lane >> 4;
    const int l15  = lane & 15;
    const int lr   = lane >> 3;
    const int lcs  = (((lane & 7) ^ lr) << 3);

    const int qt = blockIdx.x, h = blockIdx.y, b = blockIdx.z;
    const int q0 = qt * 256;
    const size_t tokbase = (size_t)b * 2048;

    bf16x8 qa[2][2];
#pragma unroll
    for (int mt = 0; mt < 2; ++mt)
#pragma unroll
        for (int kx = 0; kx < 2; ++kx)
            qa[mt][kx] = *(const bf16x8*)(Q + (tokbase + q0 + wave * 32 + mt * 16 + l15) * 1024 +
                                          h * 64 + kx * 32 + quad * 8);

    f32x4 O[2][4], Osum[2];
#pragma unroll
    for (int mt = 0; mt < 2; ++mt) {
#pragma unroll
        for (int nt = 0; nt < 4; ++nt) O[mt][nt] = f32x4{0.f, 0.f, 0.f, 0.f};
        Osum[mt] = f32x4{0.f, 0.f, 0.f, 0.f};
    }
    const bf16x8 vones = {16256, 16256, 16256, 16256, 16256, 16256, 16256, 16256};  // bf16 1.0

#define AT_STAGE(kt_, buf_)                                                                     \
    {                                                                                           \
        const int rr = wave * 8 + lr;                                                           \
        gld16(K + (tokbase + (kt_) * 64 + rr) * 1024 + h * 64 + lcs, &Kl[buf_][wave * 512]);    \
        gld16(Vt + ((size_t)(b * 1024 + h * 64 + rr)) * 2048 + (kt_) * 64 + lcs,                \
              &Vl[buf_][wave * 512]);                                                           \
    }

    AT_STAGE(0, 0)
    for (int kt = 0; kt < 32; ++kt) {
        const int buf = kt & 1;
        __syncthreads();                     // publishes buf (drains prefetch vmcnt)
        if (kt < 31) AT_STAGE(kt + 1, buf ^ 1)

        // S^T = K @ Q^T  (C layout: row=quad*4+r is K-COL, col=lane&15 is Q-ROW)
        f32x4 St[4][2];
#pragma unroll
        for (int nt = 0; nt < 4; ++nt)
#pragma unroll
            for (int mt = 0; mt < 2; ++mt) St[nt][mt] = f32x4{0.f, 0.f, 0.f, 0.f};
#pragma unroll
        for (int kx = 0; kx < 2; ++kx) {
            bf16x8 kb[4];
#pragma unroll
            for (int nt = 0; nt < 4; ++nt)
                kb[nt] = *(const bf16x8*)&Kl[buf][swz(nt * 16 + l15, kx * 4 + quad)];
#pragma unroll
            for (int nt = 0; nt < 4; ++nt)
#pragma unroll
                for (int mt = 0; mt < 2; ++mt)
                    St[nt][mt] = __builtin_amdgcn_mfma_f32_16x16x32_bf16(kb[nt], qa[mt][kx], St[nt][mt], 0, 0, 0);
        }

        // raw v_exp_f32 (scores pre-scaled by log2e) + perm-pack -> b64 write
#pragma unroll
        for (int mt = 0; mt < 2; ++mt) {
#pragma unroll
            for (int nt = 0; nt < 4; ++nt) {
                float p0 = __builtin_amdgcn_exp2f(St[nt][mt][0]);
                float p1 = __builtin_amdgcn_exp2f(St[nt][mt][1]);
                float p2 = __builtin_amdgcn_exp2f(St[nt][mt][2]);
                float p3 = __builtin_amdgcn_exp2f(St[nt][mt][3]);
                *(uint2*)&Pl[wave][mt * 16 + l15][nt * 16 + quad * 4] =
                    make_uint2(pack2bf(p0, p1), pack2bf(p2, p3));
            }
        }

        // O += P @ V ; Osum += P @ ones  (row-sums on the MFMA pipe)
#pragma unroll
        for (int kx = 0; kx < 2; ++kx) {
            bf16x8 pa[2], vb[4];
#pragma unroll
            for (int mt = 0; mt < 2; ++mt)
                pa[mt] = *(const bf16x8*)&Pl[wave][mt * 16 + l15][kx * 32 + quad * 8];
#pragma unroll
            for (int nt = 0; nt < 4; ++nt)
                vb[nt] = *(const bf16x8*)&Vl[buf][swz(nt * 16 + l15, kx * 4 + quad)];
#pragma unroll
            for (int mt = 0; mt < 2; ++mt) {
#pragma unroll
                for (int nt = 0; nt < 4; ++nt)
                    O[mt][nt] = __builtin_amdgcn_mfma_f32_16x16x32_bf16(pa[mt], vb[nt], O[mt][nt], 0, 0, 0);
                Osum[mt] = __builtin_amdgcn_mfma_f32_16x16x32_bf16(pa[mt], vones, Osum[mt], 0, 0, 0);
            }
        }
    }
#undef AT_STAGE

    // normalize + store ctx; O C-layout rows = quad*4+r match Osum rows exactly
#pragma unroll
    for (int mt = 0; mt < 2; ++mt) {
#pragma unroll
        for (int r = 0; r < 4; ++r) {
            const float inv = 1.0f / Osum[mt][r];
            const int row   = q0 + wave * 32 + mt * 16 + quad * 4 + r;
            const size_t base = (tokbase + row) * 1024 + h * 64;
#pragma unroll
            for (int nt = 0; nt < 4; ++nt)
                Ctx[base + nt * 16 + l15] = f2bf(O[mt][nt][r] * inv);
        }
    }
}

// ---------------------------------------------------------------- launch
extern "C" void kernel_launch(void* const* d_in, const int* in_sizes, int n_in,
                              void* d_out, int out_size, void* d_ws, size_t ws_size,
                              hipStream_t stream) {
    (void)in_sizes; (void)n_in; (void)out_size; (void)ws_size;
    const float* X  = (const float*)d_in[0];
    const float* Wq = (const float*)d_in[1];
    const float* bq = (const float*)d_in[2];
    const float* Wk = (const float*)d_in[3];
    const float* bk = (const float*)d_in[4];
    const float* Wv = (const float*)d_in[5];
    const float* bv = (const float*)d_in[6];
    const float* Wo = (const float*)d_in[7];
    const float* bo = (const float*)d_in[8];

    char* ws = (char*)d_ws;
    unsigned short* Xb    = (unsigned short*)(ws);                        // 16 MB (aliased as Ctx)
    unsigned short* Qb    = (unsigned short*)(ws + (size_t)16 * 1048576); // 16 MB
    unsigned short* Kb    = (unsigned short*)(ws + (size_t)32 * 1048576); // 16 MB
    unsigned short* Vt    = (unsigned short*)(ws + (size_t)48 * 1048576); // 16 MB
    unsigned short* Wqkvb = (unsigned short*)(ws + (size_t)64 * 1048576); // 6 MB
    unsigned short* Wob   = (unsigned short*)(ws + (size_t)70 * 1048576); // 2 MB
    unsigned short* Ctx   = Xb;  // X dead after QKV GEMM (stream-ordered)

    castall<<<dim3(12288), 256, 0, stream>>>(X, Wq, Wk, Wv, Wo, Xb, Wqkvb, Wob);
    gemm_qkv<<<dim3(12, 32), 512, 0, stream>>>(Xb, Wqkvb, bq, bk, bv, Qb, Kb, Vt);
    attn<<<dim3(8, 16, 4), 512, 0, stream>>>(Qb, Kb, Vt, Ctx);
    gemm_out<<<dim3(8, 64), 256, 0, stream>>>(Ctx, Wob, bo, (float*)d_out);
}

// Round 2
// 281.706 us; speedup vs baseline: 1.0403x; 1.0403x over previous
//
#include <hip/hip_runtime.h>
#include <stdint.h>

// Problem constants: B=4, S=2048, D=1024, H=1024, heads=16, d_k=64.
// Pipeline: fused cast->bf16, fused QKV GEMM (256^2-tile counted-vmcnt
// pipelined MFMA w/ compiler-derived lgkm waits, XCD-swizzled grid,
// LDS-bounced coalesced epilogues, V transposed per head),
// flash attention (MFMA, no-max exp2 softmax, S^T trick, MFMA row-sums,
// 256-q tile / 8 waves, single-barrier dbuf K/V prefetch),
// out GEMM (m97 2-barrier, f32 out).
// LDS tiles XOR-swizzled (granule g of row r at g^(r&7)) -> conflict-free b128.

using bf16x8 = __attribute__((ext_vector_type(8))) short;   // 8 bf16 = 4 VGPRs
using f32x4  = __attribute__((ext_vector_type(4))) float;   // MFMA C/D frag

#define QSCALE 0.18033688f  // 1/sqrt(64) * log2(e): scores come out log2-scaled -> exp2

__device__ __forceinline__ unsigned short f2bf(float f) {
    unsigned u = __builtin_bit_cast(unsigned, f);
    u += 0x7fffu + ((u >> 16) & 1u);          // RNE
    return (unsigned short)(u >> 16);
}

// pack two f32 -> two bf16 in one dword: round-to-nearest (ties away) + v_perm
__device__ __forceinline__ unsigned pack2bf(float f0, float f1) {
    unsigned u0 = __builtin_bit_cast(unsigned, f0) + 0x8000u;
    unsigned u1 = __builtin_bit_cast(unsigned, f1) + 0x8000u;
    return __builtin_amdgcn_perm(u1, u0, 0x07060302);  // {hi16(u1),hi16(u0)}
}

// async global->LDS, 16B per lane; LDS dest = wave-uniform base + lane*16
__device__ __forceinline__ void gld16(const void* g, void* l) {
    void* gnc = (void*)g;
    __builtin_amdgcn_global_load_lds((__attribute__((address_space(1))) void*)gnc,
                                     (__attribute__((address_space(3))) void*)l,
                                     16, 0, 0);
}

// swizzled LDS short-offset for (row R, 16B-granule g) in a 64-short-row tile
__device__ __forceinline__ int swz(int R, int g) {
    return R * 64 + ((g ^ (R & 7)) << 3);
}

// ---------------------------------------------------------------- fused casts
__global__ void castall(const float* __restrict__ X, const float* __restrict__ Wq,
                        const float* __restrict__ Wk, const float* __restrict__ Wv,
                        const float* __restrict__ Wo, unsigned short* __restrict__ Xb,
                        unsigned short* __restrict__ Wqkvb, unsigned short* __restrict__ Wob) {
    const int bx = blockIdx.x;
    const float* src; unsigned short* dst; int idx;
    if (bx < 8192) { src = X; dst = Xb; idx = bx * 256 + threadIdx.x; }
    else {
        const int r = bx - 8192, w = r >> 10;
        idx = (r & 1023) * 256 + threadIdx.x;
        src = (w == 0) ? Wq : (w == 1) ? Wk : (w == 2) ? Wv : Wo;
        dst = (w == 3) ? Wob : Wqkvb + (size_t)w * 1048576;
    }
    float4 v = ((const float4*)src)[idx];
    ((uint2*)dst)[idx] = make_uint2(pack2bf(v.x, v.y), pack2bf(v.z, v.w));
}

// ---------------------------------------------------------------- fused QKV GEMM
// A: (8192,1024) bf16. Wqkv: 3 stacked (1024,1024) bf16 = one (3072,1024).
// 256x256 tile, BK=64, 8 waves (2Mx4N, per-wave 128x64), 128 KiB LDS dbuf.
// Counted-vmcnt 4-phase schedule per K-tile t (buf b = t&1):
//   ph0: read B(all 8 frags)+A(m0,m1); stage (t+1).A0 -> buf b^1
//   ph1: read A(m2,m3);               stage (t+1).A1 -> buf b^1
//   ph2: read A(m4,m5);               stage (t+2).B0 -> buf b   (B consumed @ph0)
//   ph3: read A(m6,m7);               stage (t+2).B1 -> buf b ; s_waitcnt vmcnt(4)
//   each phase: barrier; setprio(1); 16 MFMA; setprio(0); barrier
// lgkm waits are COMPILER-DERIVED (counted, interleaved with MFMA) -- R1's
// blunt lgkmcnt(0)+sched_barrier(0) per phase serialized LDS-return against
// MFMA (MfmaUtil 22%). Reads are use-bound within their phase (every bfr/afr
// reg feeds an MFMA in the same phase), so no read can sink past the staging
// overwrite 2+ phases later; vmcnt(4) certifies tile t+1 staged. Grid is
// XCD-swizzled (384 blocks, 48/XCD = 4 complete A-row-panels) for L2 reuse.
// Epilogue bounces acc through the dead 128 KiB staging LDS (2 x 128-row
// passes) for coalesced b128 stores; Q scaled by QSCALE; V stored transposed
// per head: Vt[(b*1024 + n)*2048 + s].
__global__ __launch_bounds__(512, 2) void gemm_qkv(const unsigned short* __restrict__ A,
                                                   const unsigned short* __restrict__ Wqkv,
                                                   const float* __restrict__ bq,
                                                   const float* __restrict__ bk,
                                                   const float* __restrict__ bv,
                                                   unsigned short* __restrict__ Qb,
                                                   unsigned short* __restrict__ Kb,
                                                   unsigned short* __restrict__ Vt) {
    __shared__ alignas(16) unsigned short smem[65536];   // 128 KiB: [buf][A|B][256][64]

    const int tid  = threadIdx.x;
    const int lane = tid & 63;
    const int w    = tid >> 6;          // wave 0..7
    const int quad = lane >> 4;
    const int l15  = lane & 15;
    const int lr   = lane >> 3;
    const int lcs  = (((lane & 7) ^ lr) << 3);
    const int wm   = w >> 2;            // 0..1  (M position, 128 rows)
    const int wn   = w & 3;             // 0..3  (N position, 64 cols)

    // XCD-aware bijective swizzle: nwg=384, 384%8==0 -> wg=(orig%8)*48+orig/8.
    // XCD x owns tiles [48x,48x+48) = 4 complete A-row-panels (12 cols each).
    int wg = blockIdx.x;
    wg = (wg & 7) * 48 + (wg >> 3);
    const int bxx = wg % 12, byy = wg / 12;
    const int col0 = bxx * 256;          // output col / W row
    const int row0 = byy * 256;          // token row

    // per-thread staging source bases (row group i=0); +8*1024 shorts for i=1
    const unsigned short* aS = A    + (size_t)(row0 + w * 16 + lr) * 1024 + lcs;
    const unsigned short* bS = Wqkv + (size_t)(col0 + w * 16 + lr) * 1024 + lcs;
    const int dstW = w * 1024;          // wave's 16-row slice within a 128-row half

// stage one half-tile (128 rows x 64 k) : 2 x gld16 per thread
#define STG_A(t_, h_, b_)                                                              \
    { const unsigned short* s_ = aS + (size_t)(h_) * 131072 + (t_) * 64;               \
      gld16(s_,            &smem[(b_) * 32768 + (h_) * 8192 + dstW]);                  \
      gld16(s_ + 8 * 1024, &smem[(b_) * 32768 + (h_) * 8192 + dstW + 512]); }
#define STG_B(t_, h_, b_)                                                              \
    { const unsigned short* s_ = bS + (size_t)(h_) * 131072 + (t_) * 64;               \
      gld16(s_,            &smem[(b_) * 32768 + 16384 + (h_) * 8192 + dstW]);          \
      gld16(s_ + 8 * 1024, &smem[(b_) * 32768 + 16384 + (h_) * 8192 + dstW + 512]); }

    f32x4 acc[8][4];
#pragma unroll
    for (int i = 0; i < 8; i++)
#pragma unroll
        for (int j = 0; j < 4; j++) acc[i][j] = f32x4{0.f, 0.f, 0.f, 0.f};

    // prologue: tile0 fully + tile1's B halves; wait tile0 (leave T1.B in flight)
    STG_A(0, 0, 0) STG_A(0, 1, 0) STG_B(0, 0, 0) STG_B(0, 1, 0)
    STG_B(1, 0, 1) STG_B(1, 1, 1)
    asm volatile("s_waitcnt vmcnt(4)" ::: "memory");
    __builtin_amdgcn_s_barrier();

    for (int t = 0; t < 16; ++t) {
        const int b = t & 1;
        unsigned short* bufA = smem + b * 32768;
        unsigned short* bufB = bufA + 16384;
        bf16x8 bfr[4][2];
#pragma unroll
        for (int p = 0; p < 4; ++p) {
            bf16x8 afr[2][2];
            if (p == 0) {
#pragma unroll
                for (int nf = 0; nf < 4; ++nf)
#pragma unroll
                    for (int kx = 0; kx < 2; ++kx)
                        bfr[nf][kx] = *(const bf16x8*)&bufB[swz(wn * 64 + nf * 16 + l15, kx * 4 + quad)];
            }
#pragma unroll
            for (int mi = 0; mi < 2; ++mi)
#pragma unroll
                for (int kx = 0; kx < 2; ++kx)
                    afr[mi][kx] = *(const bf16x8*)&bufA[swz(wm * 128 + (p * 2 + mi) * 16 + l15, kx * 4 + quad)];

            if (p == 0)      { if (t < 15) STG_A(t + 1, 0, b ^ 1) }
            else if (p == 1) { if (t < 15) STG_A(t + 1, 1, b ^ 1) }
            else if (p == 2) { if (t < 14) STG_B(t + 2, 0, b) }
            else {
                if (t < 14) {
                    STG_B(t + 2, 1, b)
                    asm volatile("s_waitcnt vmcnt(4)" ::: "memory");
                } else if (t == 14) {
                    asm volatile("s_waitcnt vmcnt(0)" ::: "memory");
                }
            }
            __builtin_amdgcn_s_barrier();
            __builtin_amdgcn_s_setprio(1);
#pragma unroll
            for (int kx = 0; kx < 2; ++kx)
#pragma unroll
                for (int mi = 0; mi < 2; ++mi)
#pragma unroll
                    for (int nf = 0; nf < 4; ++nf)
                        acc[p * 2 + mi][nf] = __builtin_amdgcn_mfma_f32_16x16x32_bf16(
                            afr[mi][kx], bfr[nf][kx], acc[p * 2 + mi][nf], 0, 0, 0);
            __builtin_amdgcn_s_setprio(0);
            __builtin_amdgcn_s_barrier();
        }
    }
#undef STG_A
#undef STG_B

    // ---- epilogue: bounce through LDS (dead staging buffers) for b128 stores
    const int nb   = col0 >> 10;             // 0=Q 1=K 2=V
    const int colq = col0 & 1023;
    const float* bias = (nb == 0) ? bq : (nb == 1) ? bk : bv;

    if (nb != 2) {
        const float sc = (nb == 0) ? QSCALE : 1.0f;
        unsigned short* C = (nb == 0) ? Qb : Kb;
#pragma unroll
        for (int h = 0; h < 2; ++h) {
            if (wm == h) {                   // OT[128][264]: rows of this half
#pragma unroll
                for (int mf = 0; mf < 8; ++mf)
#pragma unroll
                    for (int nf = 0; nf < 4; ++nf) {
                        const int ct  = wn * 64 + nf * 16 + l15;
                        const float bvv = bias[colq + ct];
                        const int rt  = mf * 16 + quad * 4;
#pragma unroll
                        for (int r = 0; r < 4; ++r)
                            smem[(rt + r) * 264 + ct] = f2bf((acc[mf][nf][r] + bvv) * sc);
                    }
            }
            __syncthreads();
            const int rr = tid >> 2, qq = tid & 3;
            unsigned short* gdst = C + (size_t)(row0 + h * 128 + rr) * 1024 + colq + qq * 64;
#pragma unroll
            for (int j = 0; j < 8; ++j)
                *(bf16x8*)(gdst + j * 8) = *(const bf16x8*)&smem[rr * 264 + qq * 64 + j * 8];
            if (h == 0) __syncthreads();
        }
    } else {
        const int bb = row0 >> 11, s0 = row0 & 2047;
#pragma unroll
        for (int h = 0; h < 2; ++h) {
            if (wm == h) {                   // OT[256][136]: transposed (d, s) half
#pragma unroll
                for (int mf = 0; mf < 8; ++mf)
#pragma unroll
                    for (int nf = 0; nf < 4; ++nf) {
                        const int ct  = wn * 64 + nf * 16 + l15;
                        const float bvv = bias[colq + ct];
                        const int st  = mf * 16 + quad * 4;
                        *(uint2*)&smem[ct * 136 + st] =
                            make_uint2(pack2bf(acc[mf][nf][0] + bvv, acc[mf][nf][1] + bvv),
                                       pack2bf(acc[mf][nf][2] + bvv, acc[mf][nf][3] + bvv));
                    }
            }
            __syncthreads();
            const int c = tid >> 1, hs = tid & 1;
            unsigned short* gdst = Vt + ((size_t)(bb * 1024 + colq + c)) * 2048 + s0 + h * 128 + hs * 64;
#pragma unroll
            for (int j = 0; j < 8; ++j)
                *(bf16x8*)(gdst + j * 8) = *(const bf16x8*)&smem[c * 136 + hs * 64 + j * 8];
            if (h == 0) __syncthreads();
        }
    }
}

// ---------------------------------------------------------------- out GEMM (f32 out)
// R4 form (2-barrier m97): R5's dbuf variant regressed ~14us.
__global__ __launch_bounds__(256) void gemm_out(const unsigned short* __restrict__ A,
                                                const unsigned short* __restrict__ W,
                                                const float* __restrict__ bias,
                                                float* __restrict__ C) {
    __shared__ alignas(16) unsigned short sA[128 * 64];
    __shared__ alignas(16) unsigned short sB[128 * 64];
    const int tid  = threadIdx.x;
    const int lane = tid & 63;
    const int wave = tid >> 6;
    const int quad = lane >> 4;
    const int l15  = lane & 15;
    const int lr   = lane >> 3;
    const int lcs  = (((lane & 7) ^ lr) << 3);
    const int row0 = blockIdx.y * 128;
    const int col0 = blockIdx.x * 128;
    const int wm = wave >> 1, wn = wave & 1;

    f32x4 acc[4][4];
#pragma unroll
    for (int i = 0; i < 4; i++)
#pragma unroll
        for (int j = 0; j < 4; j++) acc[i][j] = f32x4{0.f, 0.f, 0.f, 0.f};

    for (int kt = 0; kt < 16; ++kt) {
        const int k0 = kt * 64;
#pragma unroll
        for (int i = 0; i < 4; i++) {
            const int c = wave * 4 + i;
            const int r = c * 8 + lr;
            gld16(A + (size_t)(row0 + r) * 1024 + k0 + lcs, &sA[c * 512]);
            gld16(W + (size_t)(col0 + r) * 1024 + k0 + lcs, &sB[c * 512]);
        }
        __syncthreads();
#pragma unroll
        for (int kx = 0; kx < 2; ++kx) {
            bf16x8 a[4], b[4];
#pragma unroll
            for (int i = 0; i < 4; i++) {
                a[i] = *(const bf16x8*)&sA[swz(wm * 64 + i * 16 + l15, kx * 4 + quad)];
                b[i] = *(const bf16x8*)&sB[swz(wn * 64 + i * 16 + l15, kx * 4 + quad)];
            }
#pragma unroll
            for (int i = 0; i < 4; i++)
#pragma unroll
                for (int j = 0; j < 4; j++)
                    acc[i][j] = __builtin_amdgcn_mfma_f32_16x16x32_bf16(a[i], b[j], acc[i][j], 0, 0, 0);
        }
        __syncthreads();
    }

#pragma unroll
    for (int i = 0; i < 4; i++) {
#pragma unroll
        for (int j = 0; j < 4; j++) {
            const int col   = col0 + wn * 64 + j * 16 + l15;
            const float bvv = bias[col];
            const int rbase = row0 + wm * 64 + i * 16 + quad * 4;
#pragma unroll
            for (int r = 0; r < 4; r++)
                C[(size_t)(rbase + r) * 1024 + col] = acc[i][j][r] + bvv;
        }
    }
}

// ---------------------------------------------------------------- flash attention
// Q, K: (B*S, 1024) bf16; Q pre-scaled by QSCALE (fold softmax scale + log2e).
// Vt: (B*1024, 2048) bf16. Ctx out: (B*S, 1024) bf16.
// Block: 256 q-rows of one (b,h), 8 waves (512 thr); wave owns 32 q-rows.
// 32 k-tiles of 64. Single-barrier dbuf prefetch. Row-sums via MFMA
// (Osum += P @ ones) -> no scalar adds, no epilogue shuffle reduction.
__global__ __launch_bounds__(512) void attn(const unsigned short* __restrict__ Q,
                                            const unsigned short* __restrict__ K,
                                            const unsigned short* __restrict__ Vt,
                                            unsigned short* __restrict__ Ctx) {
    __shared__ alignas(16) unsigned short Kl[2][4096];     // [buf][krow][d], swizzled (8KB ea)
    __shared__ alignas(16) unsigned short Vl[2][4096];     // [buf][d][krow], swizzled
    __shared__ alignas(16) unsigned short Pl[8][32][72];   // per-wave P (36KB)

    const int tid  = threadIdx.x;
    const int lane = tid & 63;
    const int wave = tid >> 6;        // 0..7
    const int quad = lane >> 4;
    const int l15  = lane & 15;
    const int lr   = lane >> 3;
    const int lcs  = (((lane & 7) ^ lr) << 3);

    const int qt = blockIdx.x, h = blockIdx.y, b = blockIdx.z;
    const int q0 = qt * 256;
    const size_t tokbase = (size_t)b * 2048;

    bf16x8 qa[2][2];
#pragma unroll
    for (int mt = 0; mt < 2; ++mt)
#pragma unroll
        for (int kx = 0; kx < 2; ++kx)
            qa[mt][kx] = *(const bf16x8*)(Q + (tokbase + q0 + wave * 32 + mt * 16 + l15) * 1024 +
                                          h * 64 + kx * 32 + quad * 8);

    f32x4 O[2][4], Osum[2];
#pragma unroll
    for (int mt = 0; mt < 2; ++mt) {
#pragma unroll
        for (int nt = 0; nt < 4; ++nt) O[mt][nt] = f32x4{0.f, 0.f, 0.f, 0.f};
        Osum[mt] = f32x4{0.f, 0.f, 0.f, 0.f};
    }
    const bf16x8 vones = {16256, 16256, 16256, 16256, 16256, 16256, 16256, 16256};  // bf16 1.0

#define AT_STAGE(kt_, buf_)                                                                     \
    {                                                                                           \
        const int rr = wave * 8 + lr;                                                           \
        gld16(K + (tokbase + (kt_) * 64 + rr) * 1024 + h * 64 + lcs, &Kl[buf_][wave * 512]);    \
        gld16(Vt + ((size_t)(b * 1024 + h * 64 + rr)) * 2048 + (kt_) * 64 + lcs,                \
              &Vl[buf_][wave * 512]);                                                           \
    }

    AT_STAGE(0, 0)
    for (int kt = 0; kt < 32; ++kt) {
        const int buf = kt & 1;
        __syncthreads();                     // publishes buf (drains prefetch vmcnt)
        if (kt < 31) AT_STAGE(kt + 1, buf ^ 1)

        // S^T = K @ Q^T  (C layout: row=quad*4+r is K-COL, col=lane&15 is Q-ROW)
        f32x4 St[4][2];
#pragma unroll
        for (int nt = 0; nt < 4; ++nt)
#pragma unroll
            for (int mt = 0; mt < 2; ++mt) St[nt][mt] = f32x4{0.f, 0.f, 0.f, 0.f};
#pragma unroll
        for (int kx = 0; kx < 2; ++kx) {
            bf16x8 kb[4];
#pragma unroll
            for (int nt = 0; nt < 4; ++nt)
                kb[nt] = *(const bf16x8*)&Kl[buf][swz(nt * 16 + l15, kx * 4 + quad)];
#pragma unroll
            for (int nt = 0; nt < 4; ++nt)
#pragma unroll
                for (int mt = 0; mt < 2; ++mt)
                    St[nt][mt] = __builtin_amdgcn_mfma_f32_16x16x32_bf16(kb[nt], qa[mt][kx], St[nt][mt], 0, 0, 0);
        }

        // raw v_exp_f32 (scores pre-scaled by log2e) + perm-pack -> b64 write
#pragma unroll
        for (int mt = 0; mt < 2; ++mt) {
#pragma unroll
            for (int nt = 0; nt < 4; ++nt) {
                float p0 = __builtin_amdgcn_exp2f(St[nt][mt][0]);
                float p1 = __builtin_amdgcn_exp2f(St[nt][mt][1]);
                float p2 = __builtin_amdgcn_exp2f(St[nt][mt][2]);
                float p3 = __builtin_amdgcn_exp2f(St[nt][mt][3]);
                *(uint2*)&Pl[wave][mt * 16 + l15][nt * 16 + quad * 4] =
                    make_uint2(pack2bf(p0, p1), pack2bf(p2, p3));
            }
        }

        // O += P @ V ; Osum += P @ ones  (row-sums on the MFMA pipe)
#pragma unroll
        for (int kx = 0; kx < 2; ++kx) {
            bf16x8 pa[2], vb[4];
#pragma unroll
            for (int mt = 0; mt < 2; ++mt)
                pa[mt] = *(const bf16x8*)&Pl[wave][mt * 16 + l15][kx * 32 + quad * 8];
#pragma unroll
            for (int nt = 0; nt < 4; ++nt)
                vb[nt] = *(const bf16x8*)&Vl[buf][swz(nt * 16 + l15, kx * 4 + quad)];
#pragma unroll
            for (int mt = 0; mt < 2; ++mt) {
#pragma unroll
                for (int nt = 0; nt < 4; ++nt)
                    O[mt][nt] = __builtin_amdgcn_mfma_f32_16x16x32_bf16(pa[mt], vb[nt], O[mt][nt], 0, 0, 0);
                Osum[mt] = __builtin_amdgcn_mfma_f32_16x16x32_bf16(pa[mt], vones, Osum[mt], 0, 0, 0);
            }
        }
    }
#undef AT_STAGE

    // normalize + store ctx; O C-layout rows = quad*4+r match Osum rows exactly
#pragma unroll
    for (int mt = 0; mt < 2; ++mt) {
#pragma unroll
        for (int r = 0; r < 4; ++r) {
            const float inv = 1.0f / Osum[mt][r];
            const int row   = q0 + wave * 32 + mt * 16 + quad * 4 + r;
            const size_t base = (tokbase + row) * 1024 + h * 64;
#pragma unroll
            for (int nt = 0; nt < 4; ++nt)
                Ctx[base + nt * 16 + l15] = f2bf(O[mt][nt][r] * inv);
        }
    }
}

// ---------------------------------------------------------------- launch
extern "C" void kernel_launch(void* const* d_in, const int* in_sizes, int n_in,
                              void* d_out, int out_size, void* d_ws, size_t ws_size,
                              hipStream_t stream) {
    (void)in_sizes; (void)n_in; (void)out_size; (void)ws_size;
    const float* X  = (const float*)d_in[0];
    const float* Wq = (const float*)d_in[1];
    const float* bq = (const float*)d_in[2];
    const float* Wk = (const float*)d_in[3];
    const float* bk = (const float*)d_in[4];
    const float* Wv = (const float*)d_in[5];
    const float* bv = (const float*)d_in[6];
    const float* Wo = (const float*)d_in[7];
    const float* bo = (const float*)d_in[8];

    char* ws = (char*)d_ws;
    unsigned short* Xb    = (unsigned short*)(ws);                        // 16 MB (aliased as Ctx)
    unsigned short* Qb    = (unsigned short*)(ws + (size_t)16 * 1048576); // 16 MB
    unsigned short* Kb    = (unsigned short*)(ws + (size_t)32 * 1048576); // 16 MB
    unsigned short* Vt    = (unsigned short*)(ws + (size_t)48 * 1048576); // 16 MB
    unsigned short* Wqkvb = (unsigned short*)(ws + (size_t)64 * 1048576); // 6 MB
    unsigned short* Wob   = (unsigned short*)(ws + (size_t)70 * 1048576); // 2 MB
    unsigned short* Ctx   = Xb;  // X dead after QKV GEMM (stream-ordered)

    castall<<<dim3(12288), 256, 0, stream>>>(X, Wq, Wk, Wv, Wo, Xb, Wqkvb, Wob);
    gemm_qkv<<<dim3(384), 512, 0, stream>>>(Xb, Wqkvb, bq, bk, bv, Qb, Kb, Vt);
    attn<<<dim3(8, 16, 4), 512, 0, stream>>>(Qb, Kb, Vt, Ctx);
    gemm_out<<<dim3(8, 64), 256, 0, stream>>>(Ctx, Wob, bo, (float*)d_out);
}

// Round 3
// 279.065 us; speedup vs baseline: 1.0501x; 1.0095x over previous
//
#include <hip/hip_runtime.h>
#include <stdint.h>

// Problem constants: B=4, S=2048, D=1024, H=1024, heads=16, d_k=64.
// Pipeline: fused cast->bf16, fused QKV GEMM (256^2-tile counted-vmcnt
// pipelined MFMA w/ compiler-derived lgkm waits, XCD-swizzled grid,
// LDS-bounced coalesced epilogues, V transposed per head),
// flash attention (MFMA, no-max exp2 softmax, S^T trick, in-register P
// redistribution via permlane16/32_swap -- no P LDS bounce, MFMA row-sums,
// 256-q tile / 8 waves, single-barrier dbuf K/V prefetch),
// out GEMM (m97 2-barrier, f32 out).
// LDS tiles XOR-swizzled (granule g of row r at g^(r&7)) -> conflict-free b128.

using bf16x8 = __attribute__((ext_vector_type(8))) short;   // 8 bf16 = 4 VGPRs
using f32x4  = __attribute__((ext_vector_type(4))) float;   // MFMA C/D frag
using u32x4  = __attribute__((ext_vector_type(4))) unsigned;

#define QSCALE 0.18033688f  // 1/sqrt(64) * log2(e): scores come out log2-scaled -> exp2

__device__ __forceinline__ unsigned short f2bf(float f) {
    unsigned u = __builtin_bit_cast(unsigned, f);
    u += 0x7fffu + ((u >> 16) & 1u);          // RNE
    return (unsigned short)(u >> 16);
}

// pack two f32 -> two bf16 in one dword: round-to-nearest (ties away) + v_perm
__device__ __forceinline__ unsigned pack2bf(float f0, float f1) {
    unsigned u0 = __builtin_bit_cast(unsigned, f0) + 0x8000u;
    unsigned u1 = __builtin_bit_cast(unsigned, f1) + 0x8000u;
    return __builtin_amdgcn_perm(u1, u0, 0x07060302);  // {hi16(u1),hi16(u0)}
}

// async global->LDS, 16B per lane; LDS dest = wave-uniform base + lane*16
__device__ __forceinline__ void gld16(const void* g, void* l) {
    void* gnc = (void*)g;
    __builtin_amdgcn_global_load_lds((__attribute__((address_space(1))) void*)gnc,
                                     (__attribute__((address_space(3))) void*)l,
                                     16, 0, 0);
}

// swizzled LDS short-offset for (row R, 16B-granule g) in a 64-short-row tile
__device__ __forceinline__ int swz(int R, int g) {
    return R * 64 + ((g ^ (R & 7)) << 3);
}

// ---------------------------------------------------------------- fused casts
__global__ void castall(const float* __restrict__ X, const float* __restrict__ Wq,
                        const float* __restrict__ Wk, const float* __restrict__ Wv,
                        const float* __restrict__ Wo, unsigned short* __restrict__ Xb,
                        unsigned short* __restrict__ Wqkvb, unsigned short* __restrict__ Wob) {
    const int bx = blockIdx.x;
    const float* src; unsigned short* dst; int idx;
    if (bx < 8192) { src = X; dst = Xb; idx = bx * 256 + threadIdx.x; }
    else {
        const int r = bx - 8192, w = r >> 10;
        idx = (r & 1023) * 256 + threadIdx.x;
        src = (w == 0) ? Wq : (w == 1) ? Wk : (w == 2) ? Wv : Wo;
        dst = (w == 3) ? Wob : Wqkvb + (size_t)w * 1048576;
    }
    float4 v = ((const float4*)src)[idx];
    ((uint2*)dst)[idx] = make_uint2(pack2bf(v.x, v.y), pack2bf(v.z, v.w));
}

// ---------------------------------------------------------------- fused QKV GEMM
// A: (8192,1024) bf16. Wqkv: 3 stacked (1024,1024) bf16 = one (3072,1024).
// 256x256 tile, BK=64, 8 waves (2Mx4N, per-wave 128x64), 128 KiB LDS dbuf.
// Counted-vmcnt 4-phase schedule per K-tile t (buf b = t&1):
//   ph0: read B(all 8 frags)+A(m0,m1); stage (t+1).A0 -> buf b^1
//   ph1: read A(m2,m3);               stage (t+1).A1 -> buf b^1
//   ph2: read A(m4,m5);               stage (t+2).B0 -> buf b   (B consumed @ph0)
//   ph3: read A(m6,m7);               stage (t+2).B1 -> buf b ; s_waitcnt vmcnt(4)
//   each phase: barrier; setprio(1); 16 MFMA; setprio(0); barrier
// lgkm waits are COMPILER-DERIVED (counted, interleaved with MFMA) -- R1's
// blunt lgkmcnt(0)+sched_barrier(0) per phase serialized LDS-return against
// MFMA (MfmaUtil 22%). Reads are use-bound within their phase (every bfr/afr
// reg feeds an MFMA in the same phase), so no read can sink past the staging
// overwrite 2+ phases later; vmcnt(4) certifies tile t+1 staged. Grid is
// XCD-swizzled (384 blocks, 48/XCD = 4 complete A-row-panels) for L2 reuse.
// Epilogue bounces acc through the dead 128 KiB staging LDS (2 x 128-row
// passes) for coalesced b128 stores; Q scaled by QSCALE; V stored transposed
// per head: Vt[(b*1024 + n)*2048 + s].
__global__ __launch_bounds__(512, 2) void gemm_qkv(const unsigned short* __restrict__ A,
                                                   const unsigned short* __restrict__ Wqkv,
                                                   const float* __restrict__ bq,
                                                   const float* __restrict__ bk,
                                                   const float* __restrict__ bv,
                                                   unsigned short* __restrict__ Qb,
                                                   unsigned short* __restrict__ Kb,
                                                   unsigned short* __restrict__ Vt) {
    __shared__ alignas(16) unsigned short smem[65536];   // 128 KiB: [buf][A|B][256][64]

    const int tid  = threadIdx.x;
    const int lane = tid & 63;
    const int w    = tid >> 6;          // wave 0..7
    const int quad = lane >> 4;
    const int l15  = lane & 15;
    const int lr   = lane >> 3;
    const int lcs  = (((lane & 7) ^ lr) << 3);
    const int wm   = w >> 2;            // 0..1  (M position, 128 rows)
    const int wn   = w & 3;             // 0..3  (N position, 64 cols)

    // XCD-aware bijective swizzle: nwg=384, 384%8==0 -> wg=(orig%8)*48+orig/8.
    // XCD x owns tiles [48x,48x+48) = 4 complete A-row-panels (12 cols each).
    int wg = blockIdx.x;
    wg = (wg & 7) * 48 + (wg >> 3);
    const int bxx = wg % 12, byy = wg / 12;
    const int col0 = bxx * 256;          // output col / W row
    const int row0 = byy * 256;          // token row

    // per-thread staging source bases (row group i=0); +8*1024 shorts for i=1
    const unsigned short* aS = A    + (size_t)(row0 + w * 16 + lr) * 1024 + lcs;
    const unsigned short* bS = Wqkv + (size_t)(col0 + w * 16 + lr) * 1024 + lcs;
    const int dstW = w * 1024;          // wave's 16-row slice within a 128-row half

// stage one half-tile (128 rows x 64 k) : 2 x gld16 per thread
#define STG_A(t_, h_, b_)                                                              \
    { const unsigned short* s_ = aS + (size_t)(h_) * 131072 + (t_) * 64;               \
      gld16(s_,            &smem[(b_) * 32768 + (h_) * 8192 + dstW]);                  \
      gld16(s_ + 8 * 1024, &smem[(b_) * 32768 + (h_) * 8192 + dstW + 512]); }
#define STG_B(t_, h_, b_)                                                              \
    { const unsigned short* s_ = bS + (size_t)(h_) * 131072 + (t_) * 64;               \
      gld16(s_,            &smem[(b_) * 32768 + 16384 + (h_) * 8192 + dstW]);          \
      gld16(s_ + 8 * 1024, &smem[(b_) * 32768 + 16384 + (h_) * 8192 + dstW + 512]); }

    f32x4 acc[8][4];
#pragma unroll
    for (int i = 0; i < 8; i++)
#pragma unroll
        for (int j = 0; j < 4; j++) acc[i][j] = f32x4{0.f, 0.f, 0.f, 0.f};

    // prologue: tile0 fully + tile1's B halves; wait tile0 (leave T1.B in flight)
    STG_A(0, 0, 0) STG_A(0, 1, 0) STG_B(0, 0, 0) STG_B(0, 1, 0)
    STG_B(1, 0, 1) STG_B(1, 1, 1)
    asm volatile("s_waitcnt vmcnt(4)" ::: "memory");
    __builtin_amdgcn_s_barrier();

    for (int t = 0; t < 16; ++t) {
        const int b = t & 1;
        unsigned short* bufA = smem + b * 32768;
        unsigned short* bufB = bufA + 16384;
        bf16x8 bfr[4][2];
#pragma unroll
        for (int p = 0; p < 4; ++p) {
            bf16x8 afr[2][2];
            if (p == 0) {
#pragma unroll
                for (int nf = 0; nf < 4; ++nf)
#pragma unroll
                    for (int kx = 0; kx < 2; ++kx)
                        bfr[nf][kx] = *(const bf16x8*)&bufB[swz(wn * 64 + nf * 16 + l15, kx * 4 + quad)];
            }
#pragma unroll
            for (int mi = 0; mi < 2; ++mi)
#pragma unroll
                for (int kx = 0; kx < 2; ++kx)
                    afr[mi][kx] = *(const bf16x8*)&bufA[swz(wm * 128 + (p * 2 + mi) * 16 + l15, kx * 4 + quad)];

            if (p == 0)      { if (t < 15) STG_A(t + 1, 0, b ^ 1) }
            else if (p == 1) { if (t < 15) STG_A(t + 1, 1, b ^ 1) }
            else if (p == 2) { if (t < 14) STG_B(t + 2, 0, b) }
            else {
                if (t < 14) {
                    STG_B(t + 2, 1, b)
                    asm volatile("s_waitcnt vmcnt(4)" ::: "memory");
                } else if (t == 14) {
                    asm volatile("s_waitcnt vmcnt(0)" ::: "memory");
                }
            }
            __builtin_amdgcn_s_barrier();
            __builtin_amdgcn_s_setprio(1);
#pragma unroll
            for (int kx = 0; kx < 2; ++kx)
#pragma unroll
                for (int mi = 0; mi < 2; ++mi)
#pragma unroll
                    for (int nf = 0; nf < 4; ++nf)
                        acc[p * 2 + mi][nf] = __builtin_amdgcn_mfma_f32_16x16x32_bf16(
                            afr[mi][kx], bfr[nf][kx], acc[p * 2 + mi][nf], 0, 0, 0);
            __builtin_amdgcn_s_setprio(0);
            __builtin_amdgcn_s_barrier();
        }
    }
#undef STG_A
#undef STG_B

    // ---- epilogue: bounce through LDS (dead staging buffers) for b128 stores
    const int nb   = col0 >> 10;             // 0=Q 1=K 2=V
    const int colq = col0 & 1023;
    const float* bias = (nb == 0) ? bq : (nb == 1) ? bk : bv;

    if (nb != 2) {
        const float sc = (nb == 0) ? QSCALE : 1.0f;
        unsigned short* C = (nb == 0) ? Qb : Kb;
#pragma unroll
        for (int h = 0; h < 2; ++h) {
            if (wm == h) {                   // OT[128][264]: rows of this half
#pragma unroll
                for (int mf = 0; mf < 8; ++mf)
#pragma unroll
                    for (int nf = 0; nf < 4; ++nf) {
                        const int ct  = wn * 64 + nf * 16 + l15;
                        const float bvv = bias[colq + ct];
                        const int rt  = mf * 16 + quad * 4;
#pragma unroll
                        for (int r = 0; r < 4; ++r)
                            smem[(rt + r) * 264 + ct] = f2bf((acc[mf][nf][r] + bvv) * sc);
                    }
            }
            __syncthreads();
            const int rr = tid >> 2, qq = tid & 3;
            unsigned short* gdst = C + (size_t)(row0 + h * 128 + rr) * 1024 + colq + qq * 64;
#pragma unroll
            for (int j = 0; j < 8; ++j)
                *(bf16x8*)(gdst + j * 8) = *(const bf16x8*)&smem[rr * 264 + qq * 64 + j * 8];
            if (h == 0) __syncthreads();
        }
    } else {
        const int bb = row0 >> 11, s0 = row0 & 2047;
#pragma unroll
        for (int h = 0; h < 2; ++h) {
            if (wm == h) {                   // OT[256][136]: transposed (d, s) half
#pragma unroll
                for (int mf = 0; mf < 8; ++mf)
#pragma unroll
                    for (int nf = 0; nf < 4; ++nf) {
                        const int ct  = wn * 64 + nf * 16 + l15;
                        const float bvv = bias[colq + ct];
                        const int st  = mf * 16 + quad * 4;
                        *(uint2*)&smem[ct * 136 + st] =
                            make_uint2(pack2bf(acc[mf][nf][0] + bvv, acc[mf][nf][1] + bvv),
                                       pack2bf(acc[mf][nf][2] + bvv, acc[mf][nf][3] + bvv));
                    }
            }
            __syncthreads();
            const int c = tid >> 1, hs = tid & 1;
            unsigned short* gdst = Vt + ((size_t)(bb * 1024 + colq + c)) * 2048 + s0 + h * 128 + hs * 64;
#pragma unroll
            for (int j = 0; j < 8; ++j)
                *(bf16x8*)(gdst + j * 8) = *(const bf16x8*)&smem[c * 136 + hs * 64 + j * 8];
            if (h == 0) __syncthreads();
        }
    }
}

// ---------------------------------------------------------------- out GEMM (f32 out)
// R4 form (2-barrier m97): R5's dbuf variant regressed ~14us.
__global__ __launch_bounds__(256) void gemm_out(const unsigned short* __restrict__ A,
                                                const unsigned short* __restrict__ W,
                                                const float* __restrict__ bias,
                                                float* __restrict__ C) {
    __shared__ alignas(16) unsigned short sA[128 * 64];
    __shared__ alignas(16) unsigned short sB[128 * 64];
    const int tid  = threadIdx.x;
    const int lane = tid & 63;
    const int wave = tid >> 6;
    const int quad = lane >> 4;
    const int l15  = lane & 15;
    const int lr   = lane >> 3;
    const int lcs  = (((lane & 7) ^ lr) << 3);
    const int row0 = blockIdx.y * 128;
    const int col0 = blockIdx.x * 128;
    const int wm = wave >> 1, wn = wave & 1;

    f32x4 acc[4][4];
#pragma unroll
    for (int i = 0; i < 4; i++)
#pragma unroll
        for (int j = 0; j < 4; j++) acc[i][j] = f32x4{0.f, 0.f, 0.f, 0.f};

    for (int kt = 0; kt < 16; ++kt) {
        const int k0 = kt * 64;
#pragma unroll
        for (int i = 0; i < 4; i++) {
            const int c = wave * 4 + i;
            const int r = c * 8 + lr;
            gld16(A + (size_t)(row0 + r) * 1024 + k0 + lcs, &sA[c * 512]);
            gld16(W + (size_t)(col0 + r) * 1024 + k0 + lcs, &sB[c * 512]);
        }
        __syncthreads();
#pragma unroll
        for (int kx = 0; kx < 2; ++kx) {
            bf16x8 a[4], b[4];
#pragma unroll
            for (int i = 0; i < 4; i++) {
                a[i] = *(const bf16x8*)&sA[swz(wm * 64 + i * 16 + l15, kx * 4 + quad)];
                b[i] = *(const bf16x8*)&sB[swz(wn * 64 + i * 16 + l15, kx * 4 + quad)];
            }
#pragma unroll
            for (int i = 0; i < 4; i++)
#pragma unroll
                for (int j = 0; j < 4; j++)
                    acc[i][j] = __builtin_amdgcn_mfma_f32_16x16x32_bf16(a[i], b[j], acc[i][j], 0, 0, 0);
        }
        __syncthreads();
    }

#pragma unroll
    for (int i = 0; i < 4; i++) {
#pragma unroll
        for (int j = 0; j < 4; j++) {
            const int col   = col0 + wn * 64 + j * 16 + l15;
            const float bvv = bias[col];
            const int rbase = row0 + wm * 64 + i * 16 + quad * 4;
#pragma unroll
            for (int r = 0; r < 4; r++)
                C[(size_t)(rbase + r) * 1024 + col] = acc[i][j][r] + bvv;
        }
    }
}

// ---------------------------------------------------------------- flash attention
// Q, K: (B*S, 1024) bf16; Q pre-scaled by QSCALE (fold softmax scale + log2e).
// Vt: (B*1024, 2048) bf16. Ctx out: (B*S, 1024) bf16.
// Block: 256 q-rows of one (b,h), 8 waves (512 thr); wave owns 32 q-rows.
// 32 k-tiles of 64. Single-barrier dbuf prefetch. Row-sums via MFMA
// (Osum += P @ ones). P redistribution C-layout -> A-frag is done fully
// in-register: per (mt,kx), (c,d) = permlane16_swap(permlane32_swap(dA,dB))
// converts packed-bf16 St quads into PV A-frag dwords (lane-verified mapping:
// dst (l15,quad) needs src quads {2*(quad&1), 2*(quad&1)+1} of nt=2kx+(quad>>1)).
// This removes the Pl LDS bounce -- R2 counters showed its stride-72 reads
// were 8-way bank conflicts (6.29M cycles) and a serial write->wait->read
// chain; LDS drops 68->32KB, traffic -33%.
__global__ __launch_bounds__(512, 4) void attn(const unsigned short* __restrict__ Q,
                                               const unsigned short* __restrict__ K,
                                               const unsigned short* __restrict__ Vt,
                                               unsigned short* __restrict__ Ctx) {
    __shared__ alignas(16) unsigned short Kl[2][4096];     // [buf][krow][d], swizzled (8KB ea)
    __shared__ alignas(16) unsigned short Vl[2][4096];     // [buf][d][krow], swizzled

    const int tid  = threadIdx.x;
    const int lane = tid & 63;
    const int wave = tid >> 6;        // 0..7
    const int quad = lane >> 4;
    const int l15  = lane & 15;
    const int lr   = lane >> 3;
    const int lcs  = (((lane & 7) ^ lr) << 3);

    const int qt = blockIdx.x, h = blockIdx.y, b = blockIdx.z;
    const int q0 = qt * 256;
    const size_t tokbase = (size_t)b * 2048;

    bf16x8 qa[2][2];
#pragma unroll
    for (int mt = 0; mt < 2; ++mt)
#pragma unroll
        for (int kx = 0; kx < 2; ++kx)
            qa[mt][kx] = *(const bf16x8*)(Q + (tokbase + q0 + wave * 32 + mt * 16 + l15) * 1024 +
                                          h * 64 + kx * 32 + quad * 8);

    f32x4 O[2][4], Osum[2];
#pragma unroll
    for (int mt = 0; mt < 2; ++mt) {
#pragma unroll
        for (int nt = 0; nt < 4; ++nt) O[mt][nt] = f32x4{0.f, 0.f, 0.f, 0.f};
        Osum[mt] = f32x4{0.f, 0.f, 0.f, 0.f};
    }
    const bf16x8 vones = {16256, 16256, 16256, 16256, 16256, 16256, 16256, 16256};  // bf16 1.0

#define AT_STAGE(kt_, buf_)                                                                     \
    {                                                                                           \
        const int rr = wave * 8 + lr;                                                           \
        gld16(K + (tokbase + (kt_) * 64 + rr) * 1024 + h * 64 + lcs, &Kl[buf_][wave * 512]);    \
        gld16(Vt + ((size_t)(b * 1024 + h * 64 + rr)) * 2048 + (kt_) * 64 + lcs,                \
              &Vl[buf_][wave * 512]);                                                           \
    }

    AT_STAGE(0, 0)
    for (int kt = 0; kt < 32; ++kt) {
        const int buf = kt & 1;
        __syncthreads();                     // publishes buf (drains prefetch vmcnt)
        if (kt < 31) AT_STAGE(kt + 1, buf ^ 1)

        // S^T = K @ Q^T  (C layout: row=quad*4+r is K-COL, col=lane&15 is Q-ROW)
        f32x4 St[4][2];
#pragma unroll
        for (int nt = 0; nt < 4; ++nt)
#pragma unroll
            for (int mt = 0; mt < 2; ++mt) St[nt][mt] = f32x4{0.f, 0.f, 0.f, 0.f};
#pragma unroll
        for (int kx = 0; kx < 2; ++kx) {
            bf16x8 kb[4];
#pragma unroll
            for (int nt = 0; nt < 4; ++nt)
                kb[nt] = *(const bf16x8*)&Kl[buf][swz(nt * 16 + l15, kx * 4 + quad)];
#pragma unroll
            for (int nt = 0; nt < 4; ++nt)
#pragma unroll
                for (int mt = 0; mt < 2; ++mt)
                    St[nt][mt] = __builtin_amdgcn_mfma_f32_16x16x32_bf16(kb[nt], qa[mt][kx], St[nt][mt], 0, 0, 0);
        }

        // exp2 + pack: d0/d1[nt][mt] = packed bf16 of P rows (this lane's quad)
        unsigned d0[4][2], d1[4][2];
#pragma unroll
        for (int mt = 0; mt < 2; ++mt) {
#pragma unroll
            for (int nt = 0; nt < 4; ++nt) {
                float p0 = __builtin_amdgcn_exp2f(St[nt][mt][0]);
                float p1 = __builtin_amdgcn_exp2f(St[nt][mt][1]);
                float p2 = __builtin_amdgcn_exp2f(St[nt][mt][2]);
                float p3 = __builtin_amdgcn_exp2f(St[nt][mt][3]);
                d0[nt][mt] = pack2bf(p0, p1);
                d1[nt][mt] = pack2bf(p2, p3);
            }
        }

        // in-register P redistribution -> PV A-frags (no LDS round-trip):
        // dst lane (l15,quad) k=quad*8+j comes from src quads 2*(quad&1)(+1)
        // of nt=2kx+(quad>>1); permlane32 then permlane16 realizes exactly it.
        bf16x8 pa[2][2];
#pragma unroll
        for (int mt = 0; mt < 2; ++mt) {
#pragma unroll
            for (int kx = 0; kx < 2; ++kx) {
                auto rA = __builtin_amdgcn_permlane32_swap(d0[2 * kx][mt], d0[2 * kx + 1][mt], false, false);
                auto sA = __builtin_amdgcn_permlane16_swap(rA[0], rA[1], false, false);
                auto rB = __builtin_amdgcn_permlane32_swap(d1[2 * kx][mt], d1[2 * kx + 1][mt], false, false);
                auto sB = __builtin_amdgcn_permlane16_swap(rB[0], rB[1], false, false);
                u32x4 t = {sA[0], sB[0], sA[1], sB[1]};   // {j01, j23, j45, j67}
                pa[mt][kx] = __builtin_bit_cast(bf16x8, t);
            }
        }

        // O += P @ V ; Osum += P @ ones  (row-sums on the MFMA pipe)
#pragma unroll
        for (int kx = 0; kx < 2; ++kx) {
            bf16x8 vb[4];
#pragma unroll
            for (int nt = 0; nt < 4; ++nt)
                vb[nt] = *(const bf16x8*)&Vl[buf][swz(nt * 16 + l15, kx * 4 + quad)];
#pragma unroll
            for (int mt = 0; mt < 2; ++mt) {
#pragma unroll
                for (int nt = 0; nt < 4; ++nt)
                    O[mt][nt] = __builtin_amdgcn_mfma_f32_16x16x32_bf16(pa[mt][kx], vb[nt], O[mt][nt], 0, 0, 0);
                Osum[mt] = __builtin_amdgcn_mfma_f32_16x16x32_bf16(pa[mt][kx], vones, Osum[mt], 0, 0, 0);
            }
        }
    }
#undef AT_STAGE

    // normalize + store ctx; O C-layout rows = quad*4+r match Osum rows exactly
#pragma unroll
    for (int mt = 0; mt < 2; ++mt) {
#pragma unroll
        for (int r = 0; r < 4; ++r) {
            const float inv = 1.0f / Osum[mt][r];
            const int row   = q0 + wave * 32 + mt * 16 + quad * 4 + r;
            const size_t base = (tokbase + row) * 1024 + h * 64;
#pragma unroll
            for (int nt = 0; nt < 4; ++nt)
                Ctx[base + nt * 16 + l15] = f2bf(O[mt][nt][r] * inv);
        }
    }
}

// ---------------------------------------------------------------- launch
extern "C" void kernel_launch(void* const* d_in, const int* in_sizes, int n_in,
                              void* d_out, int out_size, void* d_ws, size_t ws_size,
                              hipStream_t stream) {
    (void)in_sizes; (void)n_in; (void)out_size; (void)ws_size;
    const float* X  = (const float*)d_in[0];
    const float* Wq = (const float*)d_in[1];
    const float* bq = (const float*)d_in[2];
    const float* Wk = (const float*)d_in[3];
    const float* bk = (const float*)d_in[4];
    const float* Wv = (const float*)d_in[5];
    const float* bv = (const float*)d_in[6];
    const float* Wo = (const float*)d_in[7];
    const float* bo = (const float*)d_in[8];

    char* ws = (char*)d_ws;
    unsigned short* Xb    = (unsigned short*)(ws);                        // 16 MB (aliased as Ctx)
    unsigned short* Qb    = (unsigned short*)(ws + (size_t)16 * 1048576); // 16 MB
    unsigned short* Kb    = (unsigned short*)(ws + (size_t)32 * 1048576); // 16 MB
    unsigned short* Vt    = (unsigned short*)(ws + (size_t)48 * 1048576); // 16 MB
    unsigned short* Wqkvb = (unsigned short*)(ws + (size_t)64 * 1048576); // 6 MB
    unsigned short* Wob   = (unsigned short*)(ws + (size_t)70 * 1048576); // 2 MB
    unsigned short* Ctx   = Xb;  // X dead after QKV GEMM (stream-ordered)

    castall<<<dim3(12288), 256, 0, stream>>>(X, Wq, Wk, Wv, Wo, Xb, Wqkvb, Wob);
    gemm_qkv<<<dim3(384), 512, 0, stream>>>(Xb, Wqkvb, bq, bk, bv, Qb, Kb, Vt);
    attn<<<dim3(8, 16, 4), 512, 0, stream>>>(Qb, Kb, Vt, Ctx);
    gemm_out<<<dim3(8, 64), 256, 0, stream>>>(Ctx, Wob, bo, (float*)d_out);
}

// Round 5
// 274.756 us; speedup vs baseline: 1.0666x; 1.0157x over previous
//
#include <hip/hip_runtime.h>
#include <stdint.h>

// Problem constants: B=4, S=2048, D=1024, H=1024, heads=16, d_k=64.
// Pipeline: fused cast->bf16, fused QKV GEMM (256^2-tile counted-vmcnt
// pipelined MFMA w/ compiler-derived lgkm waits, XCD-swizzled grid,
// LDS-bounced coalesced epilogues, V transposed per head),
// flash attention (MFMA, no-max exp2 softmax, S^T trick, in-register P
// redistribution via permlane16/32_swap, zero-C QK MFMA, MFMA row-sums,
// 256-q tile / 8 waves, single-barrier dbuf K/V prefetch),
// out GEMM (128x256-tile counted-vmcnt 4-phase, same discipline as QKV).
// LDS tiles XOR-swizzled (granule g of row r at g^(r&7)) -> conflict-free b128.
// NOTE (R4 lesson): v_cvt_pk_bf16_f32 inline-asm pack FAILED correctness
// (absmax 6.5e-2) -- semantics differ from assumed {lo,hi} RNE pack. Use
// pack2bf (add+perm) everywhere; guide m240 concurs ("don't hand-write").

using bf16x8 = __attribute__((ext_vector_type(8))) short;   // 8 bf16 = 4 VGPRs
using f32x4  = __attribute__((ext_vector_type(4))) float;   // MFMA C/D frag
using u32x4  = __attribute__((ext_vector_type(4))) unsigned;

#define QSCALE 0.18033688f  // 1/sqrt(64) * log2(e): scores come out log2-scaled -> exp2

__device__ __forceinline__ unsigned short f2bf(float f) {
    unsigned u = __builtin_bit_cast(unsigned, f);
    u += 0x7fffu + ((u >> 16) & 1u);          // RNE
    return (unsigned short)(u >> 16);
}

// pack two f32 -> two bf16 in one dword: round-to-nearest (ties away) + v_perm
__device__ __forceinline__ unsigned pack2bf(float f0, float f1) {
    unsigned u0 = __builtin_bit_cast(unsigned, f0) + 0x8000u;
    unsigned u1 = __builtin_bit_cast(unsigned, f1) + 0x8000u;
    return __builtin_amdgcn_perm(u1, u0, 0x07060302);  // {hi16(u1),hi16(u0)}
}

// async global->LDS, 16B per lane; LDS dest = wave-uniform base + lane*16
__device__ __forceinline__ void gld16(const void* g, void* l) {
    void* gnc = (void*)g;
    __builtin_amdgcn_global_load_lds((__attribute__((address_space(1))) void*)gnc,
                                     (__attribute__((address_space(3))) void*)l,
                                     16, 0, 0);
}

// swizzled LDS short-offset for (row R, 16B-granule g) in a 64-short-row tile
__device__ __forceinline__ int swz(int R, int g) {
    return R * 64 + ((g ^ (R & 7)) << 3);
}

// ---------------------------------------------------------------- fused casts
__global__ void castall(const float* __restrict__ X, const float* __restrict__ Wq,
                        const float* __restrict__ Wk, const float* __restrict__ Wv,
                        const float* __restrict__ Wo, unsigned short* __restrict__ Xb,
                        unsigned short* __restrict__ Wqkvb, unsigned short* __restrict__ Wob) {
    const int bx = blockIdx.x;
    const float* src; unsigned short* dst; int idx;
    if (bx < 8192) { src = X; dst = Xb; idx = bx * 256 + threadIdx.x; }
    else {
        const int r = bx - 8192, w = r >> 10;
        idx = (r & 1023) * 256 + threadIdx.x;
        src = (w == 0) ? Wq : (w == 1) ? Wk : (w == 2) ? Wv : Wo;
        dst = (w == 3) ? Wob : Wqkvb + (size_t)w * 1048576;
    }
    float4 v = ((const float4*)src)[idx];
    ((uint2*)dst)[idx] = make_uint2(pack2bf(v.x, v.y), pack2bf(v.z, v.w));
}

// ---------------------------------------------------------------- fused QKV GEMM
// A: (8192,1024) bf16. Wqkv: 3 stacked (1024,1024) bf16 = one (3072,1024).
// 256x256 tile, BK=64, 8 waves (2Mx4N, per-wave 128x64), 128 KiB LDS dbuf.
// Counted-vmcnt 4-phase schedule per K-tile t (buf b = t&1):
//   ph0: read B(all 8 frags)+A(m0,m1); stage (t+1).A0 -> buf b^1
//   ph1: read A(m2,m3);               stage (t+1).A1 -> buf b^1
//   ph2: read A(m4,m5);               stage (t+2).B0 -> buf b   (B consumed @ph0)
//   ph3: read A(m6,m7);               stage (t+2).B1 -> buf b ; s_waitcnt vmcnt(4)
//   each phase: barrier; setprio(1); 16 MFMA; setprio(0); barrier
// lgkm waits are COMPILER-DERIVED (counted, interleaved with MFMA) -- R1's
// blunt lgkmcnt(0)+sched_barrier(0) per phase serialized LDS-return against
// MFMA (MfmaUtil 22%). Reads are use-bound within their phase (every bfr/afr
// reg feeds an MFMA in the same phase), so no read can sink past the staging
// overwrite 2+ phases later; vmcnt(4) certifies tile t+1 staged. Grid is
// XCD-swizzled (384 blocks, 48/XCD = 4 complete A-row-panels) for L2 reuse.
// Epilogue bounces acc through the dead 128 KiB staging LDS (2 x 128-row
// passes) for coalesced b128 stores; Q scaled by QSCALE; V stored transposed
// per head: Vt[(b*1024 + n)*2048 + s].
__global__ __launch_bounds__(512, 2) void gemm_qkv(const unsigned short* __restrict__ A,
                                                   const unsigned short* __restrict__ Wqkv,
                                                   const float* __restrict__ bq,
                                                   const float* __restrict__ bk,
                                                   const float* __restrict__ bv,
                                                   unsigned short* __restrict__ Qb,
                                                   unsigned short* __restrict__ Kb,
                                                   unsigned short* __restrict__ Vt) {
    __shared__ alignas(16) unsigned short smem[65536];   // 128 KiB: [buf][A|B][256][64]

    const int tid  = threadIdx.x;
    const int lane = tid & 63;
    const int w    = tid >> 6;          // wave 0..7
    const int quad = lane >> 4;
    const int l15  = lane & 15;
    const int lr   = lane >> 3;
    const int lcs  = (((lane & 7) ^ lr) << 3);
    const int wm   = w >> 2;            // 0..1  (M position, 128 rows)
    const int wn   = w & 3;             // 0..3  (N position, 64 cols)

    // XCD-aware bijective swizzle: nwg=384, 384%8==0 -> wg=(orig%8)*48+orig/8.
    // XCD x owns tiles [48x,48x+48) = 4 complete A-row-panels (12 cols each).
    int wg = blockIdx.x;
    wg = (wg & 7) * 48 + (wg >> 3);
    const int bxx = wg % 12, byy = wg / 12;
    const int col0 = bxx * 256;          // output col / W row
    const int row0 = byy * 256;          // token row

    // per-thread staging source bases (row group i=0); +8*1024 shorts for i=1
    const unsigned short* aS = A    + (size_t)(row0 + w * 16 + lr) * 1024 + lcs;
    const unsigned short* bS = Wqkv + (size_t)(col0 + w * 16 + lr) * 1024 + lcs;
    const int dstW = w * 1024;          // wave's 16-row slice within a 128-row half

// stage one half-tile (128 rows x 64 k) : 2 x gld16 per thread
#define STG_A(t_, h_, b_)                                                              \
    { const unsigned short* s_ = aS + (size_t)(h_) * 131072 + (t_) * 64;               \
      gld16(s_,            &smem[(b_) * 32768 + (h_) * 8192 + dstW]);                  \
      gld16(s_ + 8 * 1024, &smem[(b_) * 32768 + (h_) * 8192 + dstW + 512]); }
#define STG_B(t_, h_, b_)                                                              \
    { const unsigned short* s_ = bS + (size_t)(h_) * 131072 + (t_) * 64;               \
      gld16(s_,            &smem[(b_) * 32768 + 16384 + (h_) * 8192 + dstW]);          \
      gld16(s_ + 8 * 1024, &smem[(b_) * 32768 + 16384 + (h_) * 8192 + dstW + 512]); }

    f32x4 acc[8][4];
#pragma unroll
    for (int i = 0; i < 8; i++)
#pragma unroll
        for (int j = 0; j < 4; j++) acc[i][j] = f32x4{0.f, 0.f, 0.f, 0.f};

    // prologue: tile0 fully + tile1's B halves; wait tile0 (leave T1.B in flight)
    STG_A(0, 0, 0) STG_A(0, 1, 0) STG_B(0, 0, 0) STG_B(0, 1, 0)
    STG_B(1, 0, 1) STG_B(1, 1, 1)
    asm volatile("s_waitcnt vmcnt(4)" ::: "memory");
    __builtin_amdgcn_s_barrier();

    for (int t = 0; t < 16; ++t) {
        const int b = t & 1;
        unsigned short* bufA = smem + b * 32768;
        unsigned short* bufB = bufA + 16384;
        bf16x8 bfr[4][2];
#pragma unroll
        for (int p = 0; p < 4; ++p) {
            bf16x8 afr[2][2];
            if (p == 0) {
#pragma unroll
                for (int nf = 0; nf < 4; ++nf)
#pragma unroll
                    for (int kx = 0; kx < 2; ++kx)
                        bfr[nf][kx] = *(const bf16x8*)&bufB[swz(wn * 64 + nf * 16 + l15, kx * 4 + quad)];
            }
#pragma unroll
            for (int mi = 0; mi < 2; ++mi)
#pragma unroll
                for (int kx = 0; kx < 2; ++kx)
                    afr[mi][kx] = *(const bf16x8*)&bufA[swz(wm * 128 + (p * 2 + mi) * 16 + l15, kx * 4 + quad)];

            if (p == 0)      { if (t < 15) STG_A(t + 1, 0, b ^ 1) }
            else if (p == 1) { if (t < 15) STG_A(t + 1, 1, b ^ 1) }
            else if (p == 2) { if (t < 14) STG_B(t + 2, 0, b) }
            else {
                if (t < 14) {
                    STG_B(t + 2, 1, b)
                    asm volatile("s_waitcnt vmcnt(4)" ::: "memory");
                } else if (t == 14) {
                    asm volatile("s_waitcnt vmcnt(0)" ::: "memory");
                }
            }
            __builtin_amdgcn_s_barrier();
            __builtin_amdgcn_s_setprio(1);
#pragma unroll
            for (int kx = 0; kx < 2; ++kx)
#pragma unroll
                for (int mi = 0; mi < 2; ++mi)
#pragma unroll
                    for (int nf = 0; nf < 4; ++nf)
                        acc[p * 2 + mi][nf] = __builtin_amdgcn_mfma_f32_16x16x32_bf16(
                            afr[mi][kx], bfr[nf][kx], acc[p * 2 + mi][nf], 0, 0, 0);
            __builtin_amdgcn_s_setprio(0);
            __builtin_amdgcn_s_barrier();
        }
    }
#undef STG_A
#undef STG_B

    // ---- epilogue: bounce through LDS (dead staging buffers) for b128 stores
    const int nb   = col0 >> 10;             // 0=Q 1=K 2=V
    const int colq = col0 & 1023;
    const float* bias = (nb == 0) ? bq : (nb == 1) ? bk : bv;

    if (nb != 2) {
        const float sc = (nb == 0) ? QSCALE : 1.0f;
        unsigned short* C = (nb == 0) ? Qb : Kb;
#pragma unroll
        for (int h = 0; h < 2; ++h) {
            if (wm == h) {                   // OT[128][264]: rows of this half
#pragma unroll
                for (int mf = 0; mf < 8; ++mf)
#pragma unroll
                    for (int nf = 0; nf < 4; ++nf) {
                        const int ct  = wn * 64 + nf * 16 + l15;
                        const float bvv = bias[colq + ct];
                        const int rt  = mf * 16 + quad * 4;
#pragma unroll
                        for (int r = 0; r < 4; ++r)
                            smem[(rt + r) * 264 + ct] = f2bf((acc[mf][nf][r] + bvv) * sc);
                    }
            }
            __syncthreads();
            const int rr = tid >> 2, qq = tid & 3;
            unsigned short* gdst = C + (size_t)(row0 + h * 128 + rr) * 1024 + colq + qq * 64;
#pragma unroll
            for (int j = 0; j < 8; ++j)
                *(bf16x8*)(gdst + j * 8) = *(const bf16x8*)&smem[rr * 264 + qq * 64 + j * 8];
            if (h == 0) __syncthreads();
        }
    } else {
        const int bb = row0 >> 11, s0 = row0 & 2047;
#pragma unroll
        for (int h = 0; h < 2; ++h) {
            if (wm == h) {                   // OT[256][136]: transposed (d, s) half
#pragma unroll
                for (int mf = 0; mf < 8; ++mf)
#pragma unroll
                    for (int nf = 0; nf < 4; ++nf) {
                        const int ct  = wn * 64 + nf * 16 + l15;
                        const float bvv = bias[colq + ct];
                        const int st  = mf * 16 + quad * 4;
                        *(uint2*)&smem[ct * 136 + st] =
                            make_uint2(pack2bf(acc[mf][nf][0] + bvv, acc[mf][nf][1] + bvv),
                                       pack2bf(acc[mf][nf][2] + bvv, acc[mf][nf][3] + bvv));
                    }
            }
            __syncthreads();
            const int c = tid >> 1, hs = tid & 1;
            unsigned short* gdst = Vt + ((size_t)(bb * 1024 + colq + c)) * 2048 + s0 + h * 128 + hs * 64;
#pragma unroll
            for (int j = 0; j < 8; ++j)
                *(bf16x8*)(gdst + j * 8) = *(const bf16x8*)&smem[c * 136 + hs * 64 + j * 8];
            if (h == 0) __syncthreads();
        }
    }
}

// ---------------------------------------------------------------- out GEMM (f32 out)
// gemm_qkv 4-phase counted-vmcnt structure. A: (8192,1024) bf16 Ctx; W:
// (1024,1024) bf16. BM=128 x BN=256, BK=64, 8 waves (2Mx4N, per-wave 64x64,
// acc[4][4]), 96 KiB LDS dbuf, grid 256 = 1 block/CU. Per K-tile t:
//   ph0: read B(8)+A(mf0);  stage A(t+1) -> b^1     (b^1.A last read t-1 ph3)
//   ph1: read A(mf1);       stage B0(t+2) -> b      (B(t) consumed @ph0)
//   ph2: read A(mf2);       stage B1(t+2) -> b
//   ph3: read A(mf3);       vmcnt(4): drain A(t+1) (issued ph0, 3 phases ago),
//                           leave B(t+2)'s 4 in flight.
//   each phase: barrier; setprio(1); 8 MFMA; setprio(0); barrier
__global__ __launch_bounds__(512, 2) void gemm_out(const unsigned short* __restrict__ A,
                                                   const unsigned short* __restrict__ W,
                                                   const float* __restrict__ bias,
                                                   float* __restrict__ C) {
    __shared__ alignas(16) unsigned short smem[49152];   // 96 KiB: [buf][A 128x64|B 256x64]

    const int tid  = threadIdx.x;
    const int lane = tid & 63;
    const int w    = tid >> 6;
    const int quad = lane >> 4;
    const int l15  = lane & 15;
    const int lr   = lane >> 3;
    const int lcs  = (((lane & 7) ^ lr) << 3);
    const int wm   = w >> 2;            // 0..1 (M, 64 rows each)
    const int wn   = w & 3;             // 0..3 (N, 64 cols each)

    // XCD swizzle: 256 blocks -> wg=(orig&7)*32+orig>>3; XCD owns 8 M-panels.
    int wg = blockIdx.x;
    wg = (wg & 7) * 32 + (wg >> 3);
    const int col0 = (wg & 3) * 256;     // N tile (4)
    const int row0 = (wg >> 2) * 128;    // M tile (64)

    const unsigned short* aS = A + (size_t)(row0 + w * 16 + lr) * 1024 + lcs;
    const unsigned short* bS = W + (size_t)(col0 + w * 16 + lr) * 1024 + lcs;
    const int dstW = w * 1024;

#define STG_AO(t_, b_)                                                                  \
    { const unsigned short* s_ = aS + (t_) * 64;                                        \
      gld16(s_,            &smem[(b_) * 24576 + dstW]);                                 \
      gld16(s_ + 8 * 1024, &smem[(b_) * 24576 + dstW + 512]); }
#define STG_BO(t_, h_, b_)                                                              \
    { const unsigned short* s_ = bS + (size_t)(h_) * 131072 + (t_) * 64;                \
      gld16(s_,            &smem[(b_) * 24576 + 8192 + (h_) * 8192 + dstW]);            \
      gld16(s_ + 8 * 1024, &smem[(b_) * 24576 + 8192 + (h_) * 8192 + dstW + 512]); }

    f32x4 acc[4][4];
#pragma unroll
    for (int i = 0; i < 4; i++)
#pragma unroll
        for (int j = 0; j < 4; j++) acc[i][j] = f32x4{0.f, 0.f, 0.f, 0.f};

    // prologue: tile0 fully (A,B0,B1) + tile1's B halves; wait tile0.
    STG_AO(0, 0) STG_BO(0, 0, 0) STG_BO(0, 1, 0)
    STG_BO(1, 0, 1) STG_BO(1, 1, 1)
    asm volatile("s_waitcnt vmcnt(4)" ::: "memory");
    __builtin_amdgcn_s_barrier();

    for (int t = 0; t < 16; ++t) {
        const int b = t & 1;
        unsigned short* bufA = smem + b * 24576;
        unsigned short* bufB = bufA + 8192;
        bf16x8 bfr[4][2];
#pragma unroll
        for (int p = 0; p < 4; ++p) {
            bf16x8 afr[2];
            if (p == 0) {
#pragma unroll
                for (int nf = 0; nf < 4; ++nf)
#pragma unroll
                    for (int kx = 0; kx < 2; ++kx)
                        bfr[nf][kx] = *(const bf16x8*)&bufB[swz(wn * 64 + nf * 16 + l15, kx * 4 + quad)];
            }
#pragma unroll
            for (int kx = 0; kx < 2; ++kx)
                afr[kx] = *(const bf16x8*)&bufA[swz(wm * 64 + p * 16 + l15, kx * 4 + quad)];

            if (p == 0)      { if (t < 15) STG_AO(t + 1, b ^ 1) }
            else if (p == 1) { if (t < 14) STG_BO(t + 2, 0, b) }
            else if (p == 2) { if (t < 14) STG_BO(t + 2, 1, b) }
            else {
                if (t < 14)      { asm volatile("s_waitcnt vmcnt(4)" ::: "memory"); }
                else if (t == 14){ asm volatile("s_waitcnt vmcnt(0)" ::: "memory"); }
            }
            __builtin_amdgcn_s_barrier();
            __builtin_amdgcn_s_setprio(1);
#pragma unroll
            for (int kx = 0; kx < 2; ++kx)
#pragma unroll
                for (int nf = 0; nf < 4; ++nf)
                    acc[p][nf] = __builtin_amdgcn_mfma_f32_16x16x32_bf16(
                        afr[kx], bfr[nf][kx], acc[p][nf], 0, 0, 0);
            __builtin_amdgcn_s_setprio(0);
            __builtin_amdgcn_s_barrier();
        }
    }
#undef STG_AO
#undef STG_BO

#pragma unroll
    for (int mf = 0; mf < 4; ++mf) {
#pragma unroll
        for (int nf = 0; nf < 4; ++nf) {
            const int col   = col0 + wn * 64 + nf * 16 + l15;
            const float bvv = bias[col];
            const int rbase = row0 + wm * 64 + mf * 16 + quad * 4;
#pragma unroll
            for (int r = 0; r < 4; r++)
                C[(size_t)(rbase + r) * 1024 + col] = acc[mf][nf][r] + bvv;
        }
    }
}

// ---------------------------------------------------------------- flash attention
// Q, K: (B*S, 1024) bf16; Q pre-scaled by QSCALE (fold softmax scale + log2e).
// Vt: (B*1024, 2048) bf16. Ctx out: (B*S, 1024) bf16.
// Block: 256 q-rows of one (b,h), 8 waves (512 thr); wave owns 32 q-rows.
// 32 k-tiles of 64. Single-barrier dbuf prefetch. Row-sums via MFMA
// (Osum += P @ ones). P redistribution C-layout -> A-frag fully in-register
// (permlane16/32_swap). Zero-C MFMA for St kx=0 (no per-kt acc init),
// hoisted LDS offsets. pack2bf (NOT cvt_pk asm -- R4 numerics failure).
__global__ __launch_bounds__(512, 4) void attn(const unsigned short* __restrict__ Q,
                                               const unsigned short* __restrict__ K,
                                               const unsigned short* __restrict__ Vt,
                                               unsigned short* __restrict__ Ctx) {
    __shared__ alignas(16) unsigned short Kl[2][4096];     // [buf][krow][d], swizzled (8KB ea)
    __shared__ alignas(16) unsigned short Vl[2][4096];     // [buf][d][krow], swizzled

    const int tid  = threadIdx.x;
    const int lane = tid & 63;
    const int wave = tid >> 6;        // 0..7
    const int quad = lane >> 4;
    const int l15  = lane & 15;
    const int lr   = lane >> 3;
    const int lcs  = (((lane & 7) ^ lr) << 3);

    const int qt = blockIdx.x, h = blockIdx.y, b = blockIdx.z;
    const int q0 = qt * 256;
    const size_t tokbase = (size_t)b * 2048;

    // hoisted swizzled LDS offsets: frag (nt,kx) at [nt*1024 + lo(kx)]
    const int lo0 = l15 * 64 + (((quad    ) ^ (l15 & 7)) << 3);
    const int lo1 = l15 * 64 + (((quad + 4) ^ (l15 & 7)) << 3);

    bf16x8 qa[2][2];
#pragma unroll
    for (int mt = 0; mt < 2; ++mt)
#pragma unroll
        for (int kx = 0; kx < 2; ++kx)
            qa[mt][kx] = *(const bf16x8*)(Q + (tokbase + q0 + wave * 32 + mt * 16 + l15) * 1024 +
                                          h * 64 + kx * 32 + quad * 8);

    f32x4 O[2][4], Osum[2];
#pragma unroll
    for (int mt = 0; mt < 2; ++mt) {
#pragma unroll
        for (int nt = 0; nt < 4; ++nt) O[mt][nt] = f32x4{0.f, 0.f, 0.f, 0.f};
        Osum[mt] = f32x4{0.f, 0.f, 0.f, 0.f};
    }
    const f32x4 z4 = {0.f, 0.f, 0.f, 0.f};   // persistent zero C-operand
    const bf16x8 vones = {16256, 16256, 16256, 16256, 16256, 16256, 16256, 16256};  // bf16 1.0

#define AT_STAGE(kt_, buf_)                                                                     \
    {                                                                                           \
        const int rr = wave * 8 + lr;                                                           \
        gld16(K + (tokbase + (kt_) * 64 + rr) * 1024 + h * 64 + lcs, &Kl[buf_][wave * 512]);    \
        gld16(Vt + ((size_t)(b * 1024 + h * 64 + rr)) * 2048 + (kt_) * 64 + lcs,                \
              &Vl[buf_][wave * 512]);                                                           \
    }

    AT_STAGE(0, 0)
    for (int kt = 0; kt < 32; ++kt) {
        const int buf = kt & 1;
        __syncthreads();                     // publishes buf (drains prefetch vmcnt)
        if (kt < 31) AT_STAGE(kt + 1, buf ^ 1)
        const unsigned short* kb_base = &Kl[buf][0];
        const unsigned short* vb_base = &Vl[buf][0];

        // S^T = K @ Q^T  (C layout: row=quad*4+r is K-COL, col=lane&15 is Q-ROW)
        // kx=0 uses the persistent zero C (no per-kt accumulator init).
        f32x4 St[4][2];
        {
            bf16x8 kb[4];
#pragma unroll
            for (int nt = 0; nt < 4; ++nt)
                kb[nt] = *(const bf16x8*)&kb_base[lo0 + nt * 1024];
#pragma unroll
            for (int nt = 0; nt < 4; ++nt)
#pragma unroll
                for (int mt = 0; mt < 2; ++mt)
                    St[nt][mt] = __builtin_amdgcn_mfma_f32_16x16x32_bf16(kb[nt], qa[mt][0], z4, 0, 0, 0);
#pragma unroll
            for (int nt = 0; nt < 4; ++nt)
                kb[nt] = *(const bf16x8*)&kb_base[lo1 + nt * 1024];
#pragma unroll
            for (int nt = 0; nt < 4; ++nt)
#pragma unroll
                for (int mt = 0; mt < 2; ++mt)
                    St[nt][mt] = __builtin_amdgcn_mfma_f32_16x16x32_bf16(kb[nt], qa[mt][1], St[nt][mt], 0, 0, 0);
        }

        // exp2 + perm-pack: d0/d1[nt][mt] = packed bf16 of P quads
        unsigned d0[4][2], d1[4][2];
#pragma unroll
        for (int mt = 0; mt < 2; ++mt) {
#pragma unroll
            for (int nt = 0; nt < 4; ++nt) {
                float p0 = __builtin_amdgcn_exp2f(St[nt][mt][0]);
                float p1 = __builtin_amdgcn_exp2f(St[nt][mt][1]);
                float p2 = __builtin_amdgcn_exp2f(St[nt][mt][2]);
                float p3 = __builtin_amdgcn_exp2f(St[nt][mt][3]);
                d0[nt][mt] = pack2bf(p0, p1);
                d1[nt][mt] = pack2bf(p2, p3);
            }
        }

        // in-register P redistribution -> PV A-frags (no LDS round-trip):
        // dst lane (l15,quad) k=quad*8+j comes from src quads 2*(quad&1)(+1)
        // of nt=2kx+(quad>>1); permlane32 then permlane16 realizes exactly it.
        bf16x8 pa[2][2];
#pragma unroll
        for (int mt = 0; mt < 2; ++mt) {
#pragma unroll
            for (int kx = 0; kx < 2; ++kx) {
                auto rA = __builtin_amdgcn_permlane32_swap(d0[2 * kx][mt], d0[2 * kx + 1][mt], false, false);
                auto sA = __builtin_amdgcn_permlane16_swap(rA[0], rA[1], false, false);
                auto rB = __builtin_amdgcn_permlane32_swap(d1[2 * kx][mt], d1[2 * kx + 1][mt], false, false);
                auto sB = __builtin_amdgcn_permlane16_swap(rB[0], rB[1], false, false);
                u32x4 t = {sA[0], sB[0], sA[1], sB[1]};   // {j01, j23, j45, j67}
                pa[mt][kx] = __builtin_bit_cast(bf16x8, t);
            }
        }

        // O += P @ V ; Osum += P @ ones  (row-sums on the MFMA pipe)
#pragma unroll
        for (int kx = 0; kx < 2; ++kx) {
            bf16x8 vb[4];
#pragma unroll
            for (int nt = 0; nt < 4; ++nt)
                vb[nt] = *(const bf16x8*)&vb_base[(kx ? lo1 : lo0) + nt * 1024];
#pragma unroll
            for (int mt = 0; mt < 2; ++mt) {
#pragma unroll
                for (int nt = 0; nt < 4; ++nt)
                    O[mt][nt] = __builtin_amdgcn_mfma_f32_16x16x32_bf16(pa[mt][kx], vb[nt], O[mt][nt], 0, 0, 0);
                Osum[mt] = __builtin_amdgcn_mfma_f32_16x16x32_bf16(pa[mt][kx], vones, Osum[mt], 0, 0, 0);
            }
        }
    }
#undef AT_STAGE

    // normalize + store ctx; O C-layout rows = quad*4+r match Osum rows exactly
#pragma unroll
    for (int mt = 0; mt < 2; ++mt) {
#pragma unroll
        for (int r = 0; r < 4; ++r) {
            const float inv = 1.0f / Osum[mt][r];
            const int row   = q0 + wave * 32 + mt * 16 + quad * 4 + r;
            const size_t base = (tokbase + row) * 1024 + h * 64;
#pragma unroll
            for (int nt = 0; nt < 4; ++nt)
                Ctx[base + nt * 16 + l15] = f2bf(O[mt][nt][r] * inv);
        }
    }
}

// ---------------------------------------------------------------- launch
extern "C" void kernel_launch(void* const* d_in, const int* in_sizes, int n_in,
                              void* d_out, int out_size, void* d_ws, size_t ws_size,
                              hipStream_t stream) {
    (void)in_sizes; (void)n_in; (void)out_size; (void)ws_size;
    const float* X  = (const float*)d_in[0];
    const float* Wq = (const float*)d_in[1];
    const float* bq = (const float*)d_in[2];
    const float* Wk = (const float*)d_in[3];
    const float* bk = (const float*)d_in[4];
    const float* Wv = (const float*)d_in[5];
    const float* bv = (const float*)d_in[6];
    const float* Wo = (const float*)d_in[7];
    const float* bo = (const float*)d_in[8];

    char* ws = (char*)d_ws;
    unsigned short* Xb    = (unsigned short*)(ws);                        // 16 MB (aliased as Ctx)
    unsigned short* Qb    = (unsigned short*)(ws + (size_t)16 * 1048576); // 16 MB
    unsigned short* Kb    = (unsigned short*)(ws + (size_t)32 * 1048576); // 16 MB
    unsigned short* Vt    = (unsigned short*)(ws + (size_t)48 * 1048576); // 16 MB
    unsigned short* Wqkvb = (unsigned short*)(ws + (size_t)64 * 1048576); // 6 MB
    unsigned short* Wob   = (unsigned short*)(ws + (size_t)70 * 1048576); // 2 MB
    unsigned short* Ctx   = Xb;  // X dead after QKV GEMM (stream-ordered)

    castall<<<dim3(12288), 256, 0, stream>>>(X, Wq, Wk, Wv, Wo, Xb, Wqkvb, Wob);
    gemm_qkv<<<dim3(384), 512, 0, stream>>>(Xb, Wqkvb, bq, bk, bv, Qb, Kb, Vt);
    attn<<<dim3(8, 16, 4), 512, 0, stream>>>(Qb, Kb, Vt, Ctx);
    gemm_out<<<dim3(256), 512, 0, stream>>>(Ctx, Wob, bo, (float*)d_out);
}